// Round 2
// baseline (1403.942 us; speedup 1.0000x reference)
//
#include <hip/hip_runtime.h>
#include <math.h>

// Problem dims
constexpr int Bn = 8, Cd = 256, HW = 4096;
constexpr int NPOS = Bn * HW;      // 32768 spatial positions

static __device__ __forceinline__ float wredsum(float v){
  #pragma unroll
  for (int d=32; d; d>>=1) v += __shfl_xor(v,d,64);
  return v;
}
static __device__ __forceinline__ float gelu_exact(float x){
  return 0.5f*x*(1.f+erff(x*0.70710678118f));
}

// ---------------------------------------------------------------------------
// channel layernorm: per (b,pos), over C=256
__global__ __launch_bounds__(256) void k_chanln(const float* __restrict__ x,
    const float* __restrict__ g, const float* __restrict__ bb, float* __restrict__ xn){
  int p = blockIdx.x*256 + threadIdx.x;
  int b = p >> 12, pos = p & 4095;
  const float* xb = x + (size_t)b*Cd*HW + pos;
  float s=0.f, ss=0.f;
  for (int c=0;c<Cd;c++){ float v = xb[(size_t)c*HW]; s+=v; ss+=v*v; }
  float mean = s*(1.f/Cd);
  float var  = ss*(1.f/Cd) - mean*mean;
  float inv  = rsqrtf(var + 1e-5f);
  float* ob = xn + (size_t)b*Cd*HW + pos;
  for (int c=0;c<Cd;c++){
    float v = xb[(size_t)c*HW];
    ob[(size_t)c*HW] = (v-mean)*inv*g[c] + bb[c];
  }
}

// ---------------------------------------------------------------------------
// generic conv1x1 GEMM: out[b][o][p] = sum_c W[o][c]*in[b][c][p] (+W2*in2) (+bias) (+resid)
template<bool TWO, bool RES>
__global__ __launch_bounds__(256) void k_conv1x1(const float* __restrict__ in,
    const float* __restrict__ in2, const float* __restrict__ W,
    const float* __restrict__ bias, const float* __restrict__ resid,
    float* __restrict__ out, int Cin, int Cout){
  int b  = blockIdx.z;
  int o0 = blockIdx.y*16;
  int p  = blockIdx.x*1024 + threadIdx.x*4;
  int Ws = TWO ? 2*Cin : Cin;
  float4 acc[16];
  #pragma unroll
  for (int i=0;i<16;i++) acc[i] = make_float4(0.f,0.f,0.f,0.f);

  const float* inb = in + (size_t)b*Cin*HW + p;
  for (int c0=0;c0<Cin;c0+=4){
    float4 x0 = *(const float4*)(inb + (size_t)c0*HW);
    float4 x1 = *(const float4*)(inb + (size_t)(c0+1)*HW);
    float4 x2 = *(const float4*)(inb + (size_t)(c0+2)*HW);
    float4 x3 = *(const float4*)(inb + (size_t)(c0+3)*HW);
    #pragma unroll
    for (int oo=0;oo<16;oo++){
      float4 wv = *(const float4*)(W + (size_t)(o0+oo)*Ws + c0);
      acc[oo].x = fmaf(wv.x,x0.x, fmaf(wv.y,x1.x, fmaf(wv.z,x2.x, fmaf(wv.w,x3.x, acc[oo].x))));
      acc[oo].y = fmaf(wv.x,x0.y, fmaf(wv.y,x1.y, fmaf(wv.z,x2.y, fmaf(wv.w,x3.y, acc[oo].y))));
      acc[oo].z = fmaf(wv.x,x0.z, fmaf(wv.y,x1.z, fmaf(wv.z,x2.z, fmaf(wv.w,x3.z, acc[oo].z))));
      acc[oo].w = fmaf(wv.x,x0.w, fmaf(wv.y,x1.w, fmaf(wv.z,x2.w, fmaf(wv.w,x3.w, acc[oo].w))));
    }
  }
  if (TWO){
    const float* in2b = in2 + (size_t)b*Cin*HW + p;
    for (int c0=0;c0<Cin;c0+=4){
      float4 x0 = *(const float4*)(in2b + (size_t)c0*HW);
      float4 x1 = *(const float4*)(in2b + (size_t)(c0+1)*HW);
      float4 x2 = *(const float4*)(in2b + (size_t)(c0+2)*HW);
      float4 x3 = *(const float4*)(in2b + (size_t)(c0+3)*HW);
      #pragma unroll
      for (int oo=0;oo<16;oo++){
        float4 wv = *(const float4*)(W + (size_t)(o0+oo)*Ws + Cin + c0);
        acc[oo].x = fmaf(wv.x,x0.x, fmaf(wv.y,x1.x, fmaf(wv.z,x2.x, fmaf(wv.w,x3.x, acc[oo].x))));
        acc[oo].y = fmaf(wv.x,x0.y, fmaf(wv.y,x1.y, fmaf(wv.z,x2.y, fmaf(wv.w,x3.y, acc[oo].y))));
        acc[oo].z = fmaf(wv.x,x0.z, fmaf(wv.y,x1.z, fmaf(wv.z,x2.z, fmaf(wv.w,x3.z, acc[oo].z))));
        acc[oo].w = fmaf(wv.x,x0.w, fmaf(wv.y,x1.w, fmaf(wv.z,x2.w, fmaf(wv.w,x3.w, acc[oo].w))));
      }
    }
  }
  size_t ob = (size_t)b*Cout*HW + (size_t)o0*HW + p;
  #pragma unroll
  for (int oo=0;oo<16;oo++){
    float bv = bias ? bias[o0+oo] : 0.f;
    float4 r = acc[oo];
    r.x+=bv; r.y+=bv; r.z+=bv; r.w+=bv;
    if (RES){
      const float4 rv = *(const float4*)(resid + (size_t)b*Cout*HW + (size_t)(o0+oo)*HW + p);
      r.x+=rv.x; r.y+=rv.y; r.z+=rv.z; r.w+=rv.w;
    }
    *(float4*)(out + ob + (size_t)oo*HW) = r;
  }
}

// ---------------------------------------------------------------------------
// l2norm along W for q & k rows (in-place); writes k_height rowsums for k.
__global__ __launch_bounds__(256) void k_l2norm(float* __restrict__ qkv,
    float* __restrict__ k_height){
  int row  = blockIdx.x*4 + (threadIdx.x>>6);
  int lane = threadIdx.x & 63;
  int part = row >> 17;               // 0 = q, 1 = k
  int rem  = row & 131071;
  int Bp   = rem >> 11;               // 0..63
  int c    = (rem >> 6) & 31;
  int h    = rem & 63;
  int b = Bp>>3, hd = Bp&7;
  float* ptr = qkv + ((size_t)b*768 + part*256 + hd*32 + c)*(size_t)HW + h*64;
  float v = ptr[lane];
  float ss = v*v, sv = v;
  #pragma unroll
  for (int d=32; d; d>>=1){ ss += __shfl_xor(ss,d,64); sv += __shfl_xor(sv,d,64); }
  float inv = 1.f / fmaxf(sqrtf(ss), 1e-12f);
  ptr[lane] = v*inv;
  if (lane==0 && part) k_height[(size_t)Bp*2048 + c*64 + h] = sv*inv;
}

// q_probe[Bp][c] = sum over plane of normalized q  (deterministic)
__global__ __launch_bounds__(256) void k_qprobe(const float* __restrict__ qkv,
    float* __restrict__ q_probe){
  int Bp = blockIdx.x >> 5;
  int c  = blockIdx.x & 31;
  int b = Bp>>3, hd = Bp&7;
  const float* qp = qkv + ((size_t)b*768 + hd*32 + c)*(size_t)HW;
  float s = 0.f;
  for (int i=threadIdx.x*4; i<HW; i+=1024){
    float4 v = *(const float4*)(qp+i);
    s += v.x+v.y+v.z+v.w;
  }
  s = wredsum(s);
  __shared__ float red[4];
  if ((threadIdx.x&63)==0) red[threadIdx.x>>6] = s;
  __syncthreads();
  if (threadIdx.x==0) q_probe[blockIdx.x] = red[0]+red[1]+red[2]+red[3];
}

// score[Bp][t] = sum_c q_probe[Bp][c] * agg[Bp][c][t]   (64 threads)
__global__ void k_score(const float* __restrict__ q_probe,
    const float* __restrict__ agg, float* __restrict__ score){
  int Bp = blockIdx.x; int t = threadIdx.x;
  float s = 0.f;
  for (int c=0;c<32;c++) s += q_probe[Bp*32+c] * agg[(size_t)Bp*2048 + c*64 + t];
  score[Bp*64+t] = s;
}

// top-16 of 64 (set semantics; order irrelevant downstream)
__global__ void k_topk(const float* __restrict__ score, int* __restrict__ idx){
  int Bp = blockIdx.x; int lane = threadIdx.x;
  float v = score[Bp*64+lane];
  for (int it=0; it<16; ++it){
    float m = v;
    #pragma unroll
    for (int d=32; d; d>>=1) m = fmaxf(m, __shfl_xor(m,d,64));
    unsigned long long mask = __ballot(v==m);
    int sel = __ffsll((unsigned long long)mask) - 1;
    if (lane==0) idx[Bp*16+it] = sel;
    if (lane==sel) v = -3.0e38f;
  }
}

// k_width[Bp][c][w] = sum_{i<16} k[Bp][c][idx_h[i]][w]
__global__ void k_kwidth(const float* __restrict__ qkv, const int* __restrict__ idx_h,
    float* __restrict__ k_width){
  int c = blockIdx.x, Bp = blockIdx.y, w = threadIdx.x;
  int b = Bp>>3, hd = Bp&7;
  const float* kp = qkv + ((size_t)b*768 + 256 + hd*32 + c)*(size_t)HW;
  float s = 0.f;
  for (int i=0;i<16;i++) s += kp[idx_h[Bp*16+i]*64 + w];
  k_width[(size_t)Bp*2048 + c*64 + w] = s;
}

// gather selected 16x16 K/V into (Bp, 256, 32) row-major tiles
__global__ __launch_bounds__(256) void k_gather(const float* __restrict__ qkv,
    const int* __restrict__ idx_h, const int* __restrict__ idx_w,
    float* __restrict__ kf, float* __restrict__ vf){
  int Bp = blockIdx.x; int b = Bp>>3, hd = Bp&7;
  __shared__ int hi[16], wj[16];
  if (threadIdx.x < 16) hi[threadIdx.x] = idx_h[Bp*16+threadIdx.x];
  else if (threadIdx.x < 32) wj[threadIdx.x-16] = idx_w[Bp*16+threadIdx.x-16];
  __syncthreads();
  const size_t base = ((size_t)b*768 + hd*32)*(size_t)HW;
  for (int e=threadIdx.x; e<8192; e+=256){
    int c = e & 31, pair = e >> 5;
    int i = pair >> 4, j = pair & 15;
    int pos = hi[i]*64 + wj[j];
    kf[(size_t)Bp*8192 + e] = qkv[base + (size_t)(256+c)*HW + pos];
    vf[(size_t)Bp*8192 + e] = qkv[base + (size_t)(512+c)*HW + pos];
  }
}

// attention: per (Bp, 256-px tile); K/V (256x32) in LDS; online softmax per px
__global__ __launch_bounds__(256) void k_attn(const float* __restrict__ qkv,
    const float* __restrict__ kf, const float* __restrict__ vf,
    float* __restrict__ outi){
  __shared__ float lk[8192];
  __shared__ float lv[8192];
  int Bp = blockIdx.y, pt = blockIdx.x;
  int b = Bp>>3, hd = Bp&7;
  for (int e=threadIdx.x; e<8192; e+=256){
    lk[e] = kf[(size_t)Bp*8192 + e];
    lv[e] = vf[(size_t)Bp*8192 + e];
  }
  __syncthreads();
  int p = pt*256 + threadIdx.x;
  const float* qb = qkv + ((size_t)b*768 + hd*32)*(size_t)HW + p;
  float qr[32];
  #pragma unroll
  for (int c=0;c<32;c++) qr[c] = qb[(size_t)c*HW];
  float m = -3.0e38f, l = 0.f;
  float acc[32];
  #pragma unroll
  for (int c=0;c<32;c++) acc[c] = 0.f;
  for (int j=0;j<256;j++){
    const float4* krow = (const float4*)&lk[j*32];
    float s = 0.f;
    #pragma unroll
    for (int c4=0;c4<8;c4++){
      float4 kv = krow[c4];
      s += qr[c4*4+0]*kv.x + qr[c4*4+1]*kv.y + qr[c4*4+2]*kv.z + qr[c4*4+3]*kv.w;
    }
    float mn = fmaxf(m, s);
    float sc = expf(m - mn);
    float pe = expf(s - mn);
    l = l*sc + pe;
    const float4* vrow = (const float4*)&lv[j*32];
    #pragma unroll
    for (int c4=0;c4<8;c4++){
      float4 vv = vrow[c4];
      acc[c4*4+0] = acc[c4*4+0]*sc + pe*vv.x;
      acc[c4*4+1] = acc[c4*4+1]*sc + pe*vv.y;
      acc[c4*4+2] = acc[c4*4+2]*sc + pe*vv.z;
      acc[c4*4+3] = acc[c4*4+3]*sc + pe*vv.w;
    }
    m = mn;
  }
  float inv = 1.f/l;
  float* ob = outi + ((size_t)b*256 + hd*32)*(size_t)HW + p;
  #pragma unroll
  for (int c=0;c<32;c++) ob[(size_t)c*HW] = acc[c]*inv;
}

// ---------------------------------------------------------------------------
// depthwise 3x3 SAME (conv branch, C=256)
__global__ __launch_bounds__(256) void k_dw3x3(const float* __restrict__ in,
    const float* __restrict__ w, const float* __restrict__ bias,
    float* __restrict__ out, int C){
  size_t idx = (size_t)blockIdx.x*256 + threadIdx.x;
  int pos = (int)(idx & 4095);
  size_t bc = idx >> 12;            // b*C + c
  int c = (int)(bc % (size_t)C);
  int h = pos>>6, wx = pos&63;
  const float* ip = in + (bc<<12);
  const float* wp = w + c*9;
  float s = bias[c];
  #pragma unroll
  for (int kh=-1; kh<=1; ++kh){
    int hh = h+kh; if ((unsigned)hh >= 64u) continue;
    #pragma unroll
    for (int kw=-1; kw<=1; ++kw){
      int wwp = wx+kw; if ((unsigned)wwp >= 64u) continue;
      s += wp[(kh+1)*3 + (kw+1)] * ip[hh*64 + wwp];
    }
  }
  out[idx] = s;
}

// ---------------------------------------------------------------------------
// Fused FFN middle: per (b,c) plane of h (C=1024):
//   h' = gelu(instnorm(h)); r = gelu(instnorm(dwconv3x3(h')+bias)); h = h' + r
// One block per plane; plane staged in LDS; all in-place on h.
__global__ __launch_bounds__(256) void k_ffn_fused(float* __restrict__ h,
    const float* __restrict__ wdw, const float* __restrict__ bdw){
  __shared__ float lds[4096];
  __shared__ float red[8];
  int plane = blockIdx.x;            // b*1024 + c
  int c = plane & 1023;
  float* hp = h + (size_t)plane*(size_t)HW;
  int t = threadIdx.x;
  int wid = t>>6, lane = t&63;

  // pass 1: load + stats
  float4 v[4];
  float s=0.f, ss=0.f;
  #pragma unroll
  for (int k2=0;k2<4;k2++){
    v[k2] = *(const float4*)(hp + k2*1024 + t*4);
    s  += v[k2].x+v[k2].y+v[k2].z+v[k2].w;
    ss += v[k2].x*v[k2].x+v[k2].y*v[k2].y+v[k2].z*v[k2].z+v[k2].w*v[k2].w;
  }
  s = wredsum(s); ss = wredsum(ss);
  if (lane==0){ red[wid]=s; red[4+wid]=ss; }
  __syncthreads();
  s  = red[0]+red[1]+red[2]+red[3];
  ss = red[4]+red[5]+red[6]+red[7];
  float mean = s*(1.f/HW);
  float inv  = rsqrtf(ss*(1.f/HW) - mean*mean + 1e-5f);

  // h' = gelu(norm) -> LDS
  #pragma unroll
  for (int k2=0;k2<4;k2++){
    int i = k2*1024 + t*4;
    lds[i+0] = gelu_exact((v[k2].x-mean)*inv);
    lds[i+1] = gelu_exact((v[k2].y-mean)*inv);
    lds[i+2] = gelu_exact((v[k2].z-mean)*inv);
    lds[i+3] = gelu_exact((v[k2].w-mean)*inv);
  }
  __syncthreads();

  // dwconv from LDS
  float w9[9];
  #pragma unroll
  for (int i=0;i<9;i++) w9[i] = wdw[c*9+i];
  float bv = bdw[c];
  float r[16];
  float s2=0.f, ss2=0.f;
  #pragma unroll
  for (int k2=0;k2<4;k2++){
    #pragma unroll
    for (int j=0;j<4;j++){
      int px = k2*1024 + t*4 + j;
      int hh = px>>6, ww = px&63;
      float acc = bv;
      #pragma unroll
      for (int kh=-1; kh<=1; ++kh){
        int h2 = hh+kh; if ((unsigned)h2 >= 64u) continue;
        #pragma unroll
        for (int kw=-1; kw<=1; ++kw){
          int w2 = ww+kw; if ((unsigned)w2 >= 64u) continue;
          acc += w9[(kh+1)*3+(kw+1)] * lds[h2*64 + w2];
        }
      }
      r[k2*4+j] = acc;
      s2 += acc; ss2 += acc*acc;
    }
  }
  s2 = wredsum(s2); ss2 = wredsum(ss2);
  __syncthreads();                    // red[] reuse
  if (lane==0){ red[wid]=s2; red[4+wid]=ss2; }
  __syncthreads();
  s2  = red[0]+red[1]+red[2]+red[3];
  ss2 = red[4]+red[5]+red[6]+red[7];
  float mean2 = s2*(1.f/HW);
  float inv2  = rsqrtf(ss2*(1.f/HW) - mean2*mean2 + 1e-5f);

  // h = h' + gelu(norm2(r))
  #pragma unroll
  for (int k2=0;k2<4;k2++){
    int i = k2*1024 + t*4;
    float4 o;
    o.x = lds[i+0] + gelu_exact((r[k2*4+0]-mean2)*inv2);
    o.y = lds[i+1] + gelu_exact((r[k2*4+1]-mean2)*inv2);
    o.z = lds[i+2] + gelu_exact((r[k2*4+2]-mean2)*inv2);
    o.w = lds[i+3] + gelu_exact((r[k2*4+3]-mean2)*inv2);
    *(float4*)(hp + i) = o;
  }
}

// instance norm over HW per (b,ch) plane (final output)
__global__ __launch_bounds__(256) void k_instnorm(const float* __restrict__ in,
    float* __restrict__ out){
  size_t base = (size_t)blockIdx.x * HW;
  const float* p = in + base;
  float s=0.f, ss=0.f;
  for (int i=threadIdx.x*4; i<HW; i+=1024){
    float4 v = *(const float4*)(p+i);
    s  += v.x+v.y+v.z+v.w;
    ss += v.x*v.x+v.y*v.y+v.z*v.z+v.w*v.w;
  }
  s = wredsum(s); ss = wredsum(ss);
  __shared__ float sh[8];
  int wid = threadIdx.x>>6;
  if ((threadIdx.x&63)==0){ sh[wid]=s; sh[4+wid]=ss; }
  __syncthreads();
  s  = sh[0]+sh[1]+sh[2]+sh[3];
  ss = sh[4]+sh[5]+sh[6]+sh[7];
  float mean = s*(1.f/HW);
  float inv  = rsqrtf(ss*(1.f/HW) - mean*mean + 1e-5f);
  for (int i=threadIdx.x*4; i<HW; i+=1024){
    float4 v = *(const float4*)(p+i);
    float4 r;
    r.x = (v.x-mean)*inv; r.y = (v.y-mean)*inv; r.z = (v.z-mean)*inv; r.w = (v.w-mean)*inv;
    *(float4*)(out + base + i) = r;
  }
}

// ---------------------------------------------------------------------------
extern "C" void kernel_launch(void* const* d_in, const int* in_sizes, int n_in,
                              void* d_out, int out_size, void* d_ws, size_t ws_size,
                              hipStream_t stream){
  const float* x      = (const float*)d_in[0];
  const float* ln_g   = (const float*)d_in[1];
  const float* ln_bb  = (const float*)d_in[2];
  const float* w_qkv  = (const float*)d_in[3];
  const float* w_out  = (const float*)d_in[4];
  const float* b_out  = (const float*)d_in[5];
  const float* w_dw   = (const float*)d_in[6];
  const float* b_dw   = (const float*)d_in[7];
  const float* w_comb = (const float*)d_in[8];
  const float* b_comb = (const float*)d_in[9];
  const float* w_ff1  = (const float*)d_in[10];
  const float* b_ff1  = (const float*)d_in[11];
  const float* w_ffdw = (const float*)d_in[12];
  const float* b_ffdw = (const float*)d_in[13];
  const float* w_ff2  = (const float*)d_in[14];
  const float* b_ff2  = (const float*)d_in[15];
  float* out = (float*)d_out;
  float* ws  = (float*)d_ws;

  // workspace layout (floats). End = 43,266,048 floats = 165.1 MiB.
  // A  = [0, 8M):  xn -> out_inner -> attn_out -> ff2out
  // B  = [8M, 32M): qkv;  Fb reuses [8M,16M) after attention
  // H  = [8M, 40M): h (after qkv fully consumed)
  // Eb = d_out (attn branch, consumed by comb conv, later final output)
  float* A   = ws;                        //  8,388,608
  float* B   = ws + 8388608ull;           // 24,117,248 (qkv)
  float* Fb  = ws + 8388608ull;           //  8,388,608 (reuse of q region)
  float* Hb  = ws + 8388608ull;           // 33,554,432 (h; reuse of qkv + 8M more)
  float* Eb  = (float*)d_out;             //  8,388,608 (attn branch scratch)
  float* sm  = ws + 41943040ull;
  float* q_probe  = sm;                   // 2048
  float* k_height = sm + 2048;            // 131072
  float* k_width  = sm + 133120;          // 131072
  float* score_r  = sm + 264192;          // 4096
  float* score_c  = sm + 268288;          // 4096
  float* kf       = sm + 272384;          // 524288
  float* vf       = sm + 796672;          // 524288
  int*   idx_h    = (int*)(sm + 1320960); // 1024 ints
  int*   idx_w    = idx_h + 1024;         // 1024 ints

  // ---- DPSA attention branch ----
  k_chanln<<<NPOS/256, 256, 0, stream>>>(x, ln_g, ln_bb, A);
  k_conv1x1<false,false><<<dim3(4,48,8), 256, 0, stream>>>(A, nullptr, w_qkv, nullptr, nullptr, B, 256, 768);
  k_l2norm<<<65536, 256, 0, stream>>>(B, k_height);
  k_qprobe<<<2048, 256, 0, stream>>>(B, q_probe);
  k_score<<<64, 64, 0, stream>>>(q_probe, k_height, score_r);
  k_topk<<<64, 64, 0, stream>>>(score_r, idx_h);
  k_kwidth<<<dim3(32,64), 64, 0, stream>>>(B, idx_h, k_width);
  k_score<<<64, 64, 0, stream>>>(q_probe, k_width, score_c);
  k_topk<<<64, 64, 0, stream>>>(score_c, idx_w);
  k_gather<<<64, 256, 0, stream>>>(B, idx_h, idx_w, kf, vf);
  k_attn<<<dim3(16,64), 256, 0, stream>>>(B, kf, vf, A);              // out_inner -> A
  k_conv1x1<false,false><<<dim3(4,16,8), 256, 0, stream>>>(A, nullptr, w_out, b_out, nullptr, Eb, 256, 256);

  // ---- conv branch + combine + residual ----
  k_dw3x3<<<(Bn*256*HW)/256, 256, 0, stream>>>(x, w_dw, b_dw, Fb, 256);
  k_conv1x1<true,true><<<dim3(4,16,8), 256, 0, stream>>>(Eb, Fb, w_comb, b_comb, x, A, 256, 256); // attn_out -> A

  // ---- feedforward ----
  k_conv1x1<false,false><<<dim3(4,64,8), 256, 0, stream>>>(A, nullptr, w_ff1, b_ff1, nullptr, Hb, 256, 1024);
  k_ffn_fused<<<Bn*1024, 256, 0, stream>>>(Hb, w_ffdw, b_ffdw);
  k_conv1x1<false,false><<<dim3(4,16,8), 256, 0, stream>>>(Hb, nullptr, w_ff2, b_ff2, nullptr, A, 1024, 256);
  k_instnorm<<<Bn*256, 256, 0, stream>>>(A, out);
}

// Round 4
// 1197.017 us; speedup vs baseline: 1.1729x; 1.1729x over previous
//
#include <hip/hip_runtime.h>
#include <math.h>

// Problem dims
constexpr int Bn = 8, Cd = 256, HW = 4096;
constexpr int NPOS = Bn * HW;

typedef __attribute__((ext_vector_type(8))) short bfrag;   // 8 bf16
typedef __attribute__((ext_vector_type(4))) float facc;    // 4 fp32

static __device__ __forceinline__ float wredsum(float v){
  #pragma unroll
  for (int d=32; d; d>>=1) v += __shfl_xor(v,d,64);
  return v;
}
static __device__ __forceinline__ float gelu_exact(float x){
  return 0.5f*x*(1.f+erff(x*0.70710678118f));
}
// split fp32 -> bf16 hi + bf16 lo (RNE both); x ~= hi + lo with ~2^-17 rel err
static __device__ __forceinline__ void split1(float x, unsigned short& h, unsigned short& l){
  unsigned u = __float_as_uint(x);
  unsigned r = (u + 0x7FFFu + ((u>>16)&1u)) & 0xFFFF0000u;
  h = (unsigned short)(r>>16);
  float rest = x - __uint_as_float(r);
  unsigned u2 = __float_as_uint(rest);
  unsigned r2 = u2 + 0x7FFFu + ((u2>>16)&1u);
  l = (unsigned short)(r2>>16);
}

// ---------------------------------------------------------------------------
// channel layernorm
__global__ __launch_bounds__(256) void k_chanln(const float* __restrict__ x,
    const float* __restrict__ g, const float* __restrict__ bb, float* __restrict__ xn){
  int p = blockIdx.x*256 + threadIdx.x;
  int b = p >> 12, pos = p & 4095;
  const float* xb = x + (size_t)b*Cd*HW + pos;
  float s=0.f, ss=0.f;
  for (int c=0;c<Cd;c++){ float v = xb[(size_t)c*HW]; s+=v; ss+=v*v; }
  float mean = s*(1.f/Cd);
  float var  = ss*(1.f/Cd) - mean*mean;
  float inv  = rsqrtf(var + 1e-5f);
  float* ob = xn + (size_t)b*Cd*HW + pos;
  for (int c=0;c<Cd;c++){
    float v = xb[(size_t)c*HW];
    ob[(size_t)c*HW] = (v-mean)*inv*g[c] + bb[c];
  }
}

// ---------------------------------------------------------------------------
// split+transpose: planar fp32 [b][Cpart][4096] -> Xt per-batch {hi[4096][Ktot], lo[4096][Ktot]}
// at channel offset coff. Batch b = b0 + blockIdx.z*bstep.
__global__ __launch_bounds__(256) void k_splitT(const float* __restrict__ in,
    unsigned short* __restrict__ xt, int Cpart, int Ktot, int coff, int b0, int bstep){
  int b = b0 + blockIdx.z*bstep;
  int c0 = blockIdx.y*64, p0 = blockIdx.x*64;
  __shared__ float t[64][65];
  const float* ip = in + ((size_t)b*Cpart + c0)*(size_t)HW + p0;
  int tr = threadIdx.x>>4, tc4 = (threadIdx.x&15)*4;
  #pragma unroll
  for (int rr=0; rr<64; rr+=16){
    float4 v = *(const float4*)(ip + (size_t)(tr+rr)*HW + tc4);
    t[tr+rr][tc4+0]=v.x; t[tr+rr][tc4+1]=v.y; t[tr+rr][tc4+2]=v.z; t[tr+rr][tc4+3]=v.w;
  }
  __syncthreads();
  unsigned short* xh = xt + (size_t)b*2u*4096u*(size_t)Ktot + (size_t)coff + c0;
  unsigned short* xl = xh + (size_t)4096u*(size_t)Ktot;
  #pragma unroll
  for (int rr=0; rr<64; rr+=16){
    int p = tr+rr;
    ushort4 hv, lv;
    split1(t[tc4+0][p], hv.x, lv.x);
    split1(t[tc4+1][p], hv.y, lv.y);
    split1(t[tc4+2][p], hv.z, lv.z);
    split1(t[tc4+3][p], hv.w, lv.w);
    size_t off = (size_t)(p0+p)*(size_t)Ktot + tc4;
    *(ushort4*)(xh + off) = hv;
    *(ushort4*)(xl + off) = lv;
  }
}

// elementwise weight split: W[n] fp32 -> wh[n], wl[n] (wl stored at wh+n)
__global__ void k_splitW(const float* __restrict__ w, unsigned short* __restrict__ wh, int n){
  int i = blockIdx.x*256 + threadIdx.x;
  if (i<n){
    unsigned short h,l; split1(w[i],h,l);
    wh[i]=h; wh[n+i]=l;
  }
}

// ---------------------------------------------------------------------------
// MFMA GEMM: out[b][o][p] = sum_c W[o][c]*X[b][c][p] (+bias)(+resid)
// W2: hi[M*K] then lo[M*K]. Xt: per batch {hi[4096][K], lo[4096][K]}.
// Block 256 thr = 4 waves (2m x 2n of 64x64). Grid (4096/128, M/128, Bn).
template<bool RES>
__global__ __launch_bounds__(256) void k_mfma(
    const unsigned short* __restrict__ W2,
    const unsigned short* __restrict__ Xt,
    const float* __restrict__ bias, const float* __restrict__ resid,
    float* __restrict__ out, int M, int K){
  int b  = blockIdx.z;
  int n0 = blockIdx.x*128;
  int m0 = blockIdx.y*128;
  int wave = threadIdx.x>>6, lane = threadIdx.x&63;
  int wm = (wave>>1)*64, wn = (wave&1)*64;
  int l15 = lane&15, half = lane>>4;
  const unsigned short* Wh = W2;
  const unsigned short* Wl = W2 + (size_t)M*K;
  const unsigned short* Xh = Xt + (size_t)b*2u*4096u*(size_t)K;
  const unsigned short* Xl = Xh + (size_t)4096u*(size_t)K;

  facc acc[4][4];
  #pragma unroll
  for (int i=0;i<4;i++)
    #pragma unroll
    for (int j=0;j<4;j++) acc[i][j] = (facc){0.f,0.f,0.f,0.f};

  const size_t wrow[4] = {
    (size_t)(m0+wm+ 0+l15)*(size_t)K, (size_t)(m0+wm+16+l15)*(size_t)K,
    (size_t)(m0+wm+32+l15)*(size_t)K, (size_t)(m0+wm+48+l15)*(size_t)K };
  const size_t xrow[4] = {
    (size_t)(n0+wn+ 0+l15)*(size_t)K, (size_t)(n0+wn+16+l15)*(size_t)K,
    (size_t)(n0+wn+32+l15)*(size_t)K, (size_t)(n0+wn+48+l15)*(size_t)K };

  for (int k0=0; k0<K; k0+=32){
    int ks = k0 + half*8;
    bfrag ah[4], al[4], bh[4], bl[4];
    #pragma unroll
    for (int i=0;i<4;i++){
      ah[i] = *(const bfrag*)(Wh + wrow[i] + ks);
      al[i] = *(const bfrag*)(Wl + wrow[i] + ks);
      bh[i] = *(const bfrag*)(Xh + xrow[i] + ks);
      bl[i] = *(const bfrag*)(Xl + xrow[i] + ks);
    }
    #pragma unroll
    for (int i=0;i<4;i++)
      #pragma unroll
      for (int j=0;j<4;j++){
        acc[i][j] = __builtin_amdgcn_mfma_f32_16x16x32_bf16(ah[i], bh[j], acc[i][j],0,0,0);
        acc[i][j] = __builtin_amdgcn_mfma_f32_16x16x32_bf16(ah[i], bl[j], acc[i][j],0,0,0);
        acc[i][j] = __builtin_amdgcn_mfma_f32_16x16x32_bf16(al[i], bh[j], acc[i][j],0,0,0);
      }
  }
  // epilogue: D row = o (col=lane&15 -> p)
  #pragma unroll
  for (int i=0;i<4;i++){
    int o = m0+wm+i*16+half*4;
    #pragma unroll
    for (int j=0;j<4;j++){
      int p = n0+wn+j*16+l15;
      size_t ob = ((size_t)b*M + o)*(size_t)HW + p;
      #pragma unroll
      for (int r=0;r<4;r++){
        float v = acc[i][j][r];
        if (bias) v += bias[o+r];
        if (RES)  v += resid[ob + (size_t)r*HW];
        out[ob + (size_t)r*HW] = v;
      }
    }
  }
}

// ---------------------------------------------------------------------------
// l2norm along W for q & k rows (in-place on Q); writes k_height rowsums for k.
__global__ __launch_bounds__(256) void k_l2norm(float* __restrict__ qkv,
    float* __restrict__ k_height){
  int row  = blockIdx.x*4 + (threadIdx.x>>6);
  int lane = threadIdx.x & 63;
  int part = row >> 17;
  int rem  = row & 131071;
  int Bp   = rem >> 11;
  int c    = (rem >> 6) & 31;
  int h    = rem & 63;
  int b = Bp>>3, hd = Bp&7;
  float* ptr = qkv + ((size_t)b*768 + part*256 + hd*32 + c)*(size_t)HW + h*64;
  float v = ptr[lane];
  float ss = v*v, sv = v;
  #pragma unroll
  for (int d=32; d; d>>=1){ ss += __shfl_xor(ss,d,64); sv += __shfl_xor(sv,d,64); }
  float inv = 1.f / fmaxf(sqrtf(ss), 1e-12f);
  ptr[lane] = v*inv;
  if (lane==0 && part) k_height[(size_t)Bp*2048 + c*64 + h] = sv*inv;
}

__global__ __launch_bounds__(256) void k_qprobe(const float* __restrict__ qkv,
    float* __restrict__ q_probe){
  int Bp = blockIdx.x >> 5;
  int c  = blockIdx.x & 31;
  int b = Bp>>3, hd = Bp&7;
  const float* qp = qkv + ((size_t)b*768 + hd*32 + c)*(size_t)HW;
  float s = 0.f;
  for (int i=threadIdx.x*4; i<HW; i+=1024){
    float4 v = *(const float4*)(qp+i);
    s += v.x+v.y+v.z+v.w;
  }
  s = wredsum(s);
  __shared__ float red[4];
  if ((threadIdx.x&63)==0) red[threadIdx.x>>6] = s;
  __syncthreads();
  if (threadIdx.x==0) q_probe[blockIdx.x] = red[0]+red[1]+red[2]+red[3];
}

__global__ void k_score(const float* __restrict__ q_probe,
    const float* __restrict__ agg, float* __restrict__ score){
  int Bp = blockIdx.x; int t = threadIdx.x;
  float s = 0.f;
  for (int c=0;c<32;c++) s += q_probe[Bp*32+c] * agg[(size_t)Bp*2048 + c*64 + t];
  score[Bp*64+t] = s;
}

__global__ void k_topk(const float* __restrict__ score, int* __restrict__ idx){
  int Bp = blockIdx.x; int lane = threadIdx.x;
  float v = score[Bp*64+lane];
  for (int it=0; it<16; ++it){
    float m = v;
    #pragma unroll
    for (int d=32; d; d>>=1) m = fmaxf(m, __shfl_xor(m,d,64));
    unsigned long long mask = __ballot(v==m);
    int sel = __ffsll((unsigned long long)mask) - 1;
    if (lane==0) idx[Bp*16+it] = sel;
    if (lane==sel) v = -3.0e38f;
  }
}

__global__ void k_kwidth(const float* __restrict__ qkv, const int* __restrict__ idx_h,
    float* __restrict__ k_width){
  int c = blockIdx.x, Bp = blockIdx.y, w = threadIdx.x;
  int b = Bp>>3, hd = Bp&7;
  const float* kp = qkv + ((size_t)b*768 + 256 + hd*32 + c)*(size_t)HW;
  float s = 0.f;
  for (int i=0;i<16;i++) s += kp[idx_h[Bp*16+i]*64 + w];
  k_width[(size_t)Bp*2048 + c*64 + w] = s;
}

__global__ __launch_bounds__(256) void k_gather(const float* __restrict__ qkv,
    const int* __restrict__ idx_h, const int* __restrict__ idx_w,
    float* __restrict__ kf, float* __restrict__ vf){
  int Bp = blockIdx.x; int b = Bp>>3, hd = Bp&7;
  __shared__ int hi[16], wj[16];
  if (threadIdx.x < 16) hi[threadIdx.x] = idx_h[Bp*16+threadIdx.x];
  else if (threadIdx.x < 32) wj[threadIdx.x-16] = idx_w[Bp*16+threadIdx.x-16];
  __syncthreads();
  const size_t base = ((size_t)b*768 + hd*32)*(size_t)HW;
  for (int e=threadIdx.x; e<8192; e+=256){
    int c = e & 31, pair = e >> 5;
    int i = pair >> 4, j = pair & 15;
    int pos = hi[i]*64 + wj[j];
    kf[(size_t)Bp*8192 + e] = qkv[base + (size_t)(256+c)*HW + pos];
    vf[(size_t)Bp*8192 + e] = qkv[base + (size_t)(512+c)*HW + pos];
  }
}

__global__ __launch_bounds__(256) void k_attn(const float* __restrict__ qkv,
    const float* __restrict__ kf, const float* __restrict__ vf,
    float* __restrict__ outi){
  __shared__ float lk[8192];
  __shared__ float lv[8192];
  int Bp = blockIdx.y, pt = blockIdx.x;
  int b = Bp>>3, hd = Bp&7;
  for (int e=threadIdx.x; e<8192; e+=256){
    lk[e] = kf[(size_t)Bp*8192 + e];
    lv[e] = vf[(size_t)Bp*8192 + e];
  }
  __syncthreads();
  int p = pt*256 + threadIdx.x;
  const float* qb = qkv + ((size_t)b*768 + hd*32)*(size_t)HW + p;
  float qr[32];
  #pragma unroll
  for (int c=0;c<32;c++) qr[c] = qb[(size_t)c*HW];
  float m = -3.0e38f, l = 0.f;
  float acc[32];
  #pragma unroll
  for (int c=0;c<32;c++) acc[c] = 0.f;
  for (int j=0;j<256;j++){
    const float4* krow = (const float4*)&lk[j*32];
    float s = 0.f;
    #pragma unroll
    for (int c4=0;c4<8;c4++){
      float4 kv = krow[c4];
      s += qr[c4*4+0]*kv.x + qr[c4*4+1]*kv.y + qr[c4*4+2]*kv.z + qr[c4*4+3]*kv.w;
    }
    float mn = fmaxf(m, s);
    float sc = expf(m - mn);
    float pe = expf(s - mn);
    l = l*sc + pe;
    const float4* vrow = (const float4*)&lv[j*32];
    #pragma unroll
    for (int c4=0;c4<8;c4++){
      float4 vv = vrow[c4];
      acc[c4*4+0] = acc[c4*4+0]*sc + pe*vv.x;
      acc[c4*4+1] = acc[c4*4+1]*sc + pe*vv.y;
      acc[c4*4+2] = acc[c4*4+2]*sc + pe*vv.z;
      acc[c4*4+3] = acc[c4*4+3]*sc + pe*vv.w;
    }
    m = mn;
  }
  float inv = 1.f/l;
  float* ob = outi + ((size_t)b*256 + hd*32)*(size_t)HW + p;
  #pragma unroll
  for (int c=0;c<32;c++) ob[(size_t)c*HW] = acc[c]*inv;
}

// ---------------------------------------------------------------------------
__global__ __launch_bounds__(256) void k_dw3x3(const float* __restrict__ in,
    const float* __restrict__ w, const float* __restrict__ bias,
    float* __restrict__ out, int C){
  size_t idx = (size_t)blockIdx.x*256 + threadIdx.x;
  int pos = (int)(idx & 4095);
  size_t bc = idx >> 12;
  int c = (int)(bc % (size_t)C);
  int h = pos>>6, wx = pos&63;
  const float* ip = in + (bc<<12);
  const float* wp = w + c*9;
  float s = bias[c];
  #pragma unroll
  for (int kh=-1; kh<=1; ++kh){
    int hh = h+kh; if ((unsigned)hh >= 64u) continue;
    #pragma unroll
    for (int kw=-1; kw<=1; ++kw){
      int wwp = wx+kw; if ((unsigned)wwp >= 64u) continue;
      s += wp[(kh+1)*3 + (kw+1)] * ip[hh*64 + wwp];
    }
  }
  out[idx] = s;
}

// ---------------------------------------------------------------------------
__global__ __launch_bounds__(256) void k_ffn_fused(float* __restrict__ h,
    const float* __restrict__ wdw, const float* __restrict__ bdw){
  __shared__ float lds[4096];
  __shared__ float red[8];
  int plane = blockIdx.x;
  int c = plane & 1023;
  float* hp = h + (size_t)plane*(size_t)HW;
  int t = threadIdx.x;
  int wid = t>>6, lane = t&63;

  float4 v[4];
  float s=0.f, ss=0.f;
  #pragma unroll
  for (int k2=0;k2<4;k2++){
    v[k2] = *(const float4*)(hp + k2*1024 + t*4);
    s  += v[k2].x+v[k2].y+v[k2].z+v[k2].w;
    ss += v[k2].x*v[k2].x+v[k2].y*v[k2].y+v[k2].z*v[k2].z+v[k2].w*v[k2].w;
  }
  s = wredsum(s); ss = wredsum(ss);
  if (lane==0){ red[wid]=s; red[4+wid]=ss; }
  __syncthreads();
  s  = red[0]+red[1]+red[2]+red[3];
  ss = red[4]+red[5]+red[6]+red[7];
  float mean = s*(1.f/HW);
  float inv  = rsqrtf(ss*(1.f/HW) - mean*mean + 1e-5f);

  #pragma unroll
  for (int k2=0;k2<4;k2++){
    int i = k2*1024 + t*4;
    lds[i+0] = gelu_exact((v[k2].x-mean)*inv);
    lds[i+1] = gelu_exact((v[k2].y-mean)*inv);
    lds[i+2] = gelu_exact((v[k2].z-mean)*inv);
    lds[i+3] = gelu_exact((v[k2].w-mean)*inv);
  }
  __syncthreads();

  float w9[9];
  #pragma unroll
  for (int i=0;i<9;i++) w9[i] = wdw[c*9+i];
  float bv = bdw[c];
  float r[16];
  float s2=0.f, ss2=0.f;
  #pragma unroll
  for (int k2=0;k2<4;k2++){
    #pragma unroll
    for (int j=0;j<4;j++){
      int px = k2*1024 + t*4 + j;
      int hh = px>>6, ww = px&63;
      float acc = bv;
      #pragma unroll
      for (int kh=-1; kh<=1; ++kh){
        int h2 = hh+kh; if ((unsigned)h2 >= 64u) continue;
        #pragma unroll
        for (int kw=-1; kw<=1; ++kw){
          int w2 = ww+kw; if ((unsigned)w2 >= 64u) continue;
          acc += w9[(kh+1)*3+(kw+1)] * lds[h2*64 + w2];
        }
      }
      r[k2*4+j] = acc;
      s2 += acc; ss2 += acc*acc;
    }
  }
  s2 = wredsum(s2); ss2 = wredsum(ss2);
  __syncthreads();
  if (lane==0){ red[wid]=s2; red[4+wid]=ss2; }
  __syncthreads();
  s2  = red[0]+red[1]+red[2]+red[3];
  ss2 = red[4]+red[5]+red[6]+red[7];
  float mean2 = s2*(1.f/HW);
  float inv2  = rsqrtf(ss2*(1.f/HW) - mean2*mean2 + 1e-5f);

  #pragma unroll
  for (int k2=0;k2<4;k2++){
    int i = k2*1024 + t*4;
    float4 o;
    o.x = lds[i+0] + gelu_exact((r[k2*4+0]-mean2)*inv2);
    o.y = lds[i+1] + gelu_exact((r[k2*4+1]-mean2)*inv2);
    o.z = lds[i+2] + gelu_exact((r[k2*4+2]-mean2)*inv2);
    o.w = lds[i+3] + gelu_exact((r[k2*4+3]-mean2)*inv2);
    *(float4*)(hp + i) = o;
  }
}

// instance norm over HW per plane; safe in-place (in==out)
__global__ __launch_bounds__(256) void k_instnorm(const float* __restrict__ in,
    float* __restrict__ out){
  size_t base = (size_t)blockIdx.x * HW;
  const float* p = in + base;
  float s=0.f, ss=0.f;
  for (int i=threadIdx.x*4; i<HW; i+=1024){
    float4 v = *(const float4*)(p+i);
    s  += v.x+v.y+v.z+v.w;
    ss += v.x*v.x+v.y*v.y+v.z*v.z+v.w*v.w;
  }
  s = wredsum(s); ss = wredsum(ss);
  __shared__ float sh[8];
  int wid = threadIdx.x>>6;
  if ((threadIdx.x&63)==0){ sh[wid]=s; sh[4+wid]=ss; }
  __syncthreads();
  s  = sh[0]+sh[1]+sh[2]+sh[3];
  ss = sh[4]+sh[5]+sh[6]+sh[7];
  float mean = s*(1.f/HW);
  float inv  = rsqrtf(ss*(1.f/HW) - mean*mean + 1e-5f);
  for (int i=threadIdx.x*4; i<HW; i+=1024){
    float4 v = *(const float4*)(p+i);
    float4 r;
    r.x = (v.x-mean)*inv; r.y = (v.y-mean)*inv; r.z = (v.z-mean)*inv; r.w = (v.w-mean)*inv;
    *(float4*)(out + base + i) = r;
  }
}

// ---------------------------------------------------------------------------
extern "C" void kernel_launch(void* const* d_in, const int* in_sizes, int n_in,
                              void* d_out, int out_size, void* d_ws, size_t ws_size,
                              hipStream_t stream){
  const float* x      = (const float*)d_in[0];
  const float* ln_g   = (const float*)d_in[1];
  const float* ln_bb  = (const float*)d_in[2];
  const float* w_qkv  = (const float*)d_in[3];
  const float* w_out  = (const float*)d_in[4];
  const float* b_out  = (const float*)d_in[5];
  const float* w_dw   = (const float*)d_in[6];
  const float* b_dw   = (const float*)d_in[7];
  const float* w_comb = (const float*)d_in[8];
  const float* b_comb = (const float*)d_in[9];
  const float* w_ff1  = (const float*)d_in[10];
  const float* b_ff1  = (const float*)d_in[11];
  const float* w_ffdw = (const float*)d_in[12];
  const float* b_ffdw = (const float*)d_in[13];
  const float* w_ff2  = (const float*)d_in[14];
  const float* b_ff2  = (const float*)d_in[15];
  float* out = (float*)d_out;
  float* ws  = (float*)d_ws;

  // ---- workspace layout (floats), ~163.5 MiB ----
  // [0,8M):   A (xn -> out_inner -> attn_out)
  // [8M,32M): Q qkv output (alive: qkv GEMM -> attn)
  // [8M,40M): Hb h (alive: ff1 -> ffn_fused -> ff2-convert)
  // [4M,36M): XT3 ff2-input (slot b sits on Hb slot b-1; SEQUENTIAL b=0..7)
  // [16M,32M):XT2 comb-input
  // [32M,40M):XTa (qkv-in / wout-in), later Fb; attention smalls at same base
  // d_out:    Eb (w_out result) -> XTb (ff1-input bf16) -> final output
  // [40M,~41.4M): W2 splits (permanent)
  float* A   = ws;
  float* Q   = ws + 8388608ull;
  float* Hb  = ws + 8388608ull;
  unsigned short* XT3 = (unsigned short*)(ws + 4194304ull);
  unsigned short* XT2 = (unsigned short*)(ws + 16777216ull);
  unsigned short* XTa = (unsigned short*)(ws + 33554432ull);
  unsigned short* XTb = (unsigned short*)d_out;
  float* Fb  = ws + 33554432ull;
  float* S   = ws + 33554432ull;          // attention smalls (dead before XTa reuse / Fb)
  float* kf       = S;                    // 524288
  float* vf       = S + 524288;           // 524288
  float* k_height = S + 1048576;          // 131072
  float* k_width  = S + 1179648;          // 131072
  float* q_probe  = S + 1310720;          // 2048
  float* score_r  = S + 1312768;          // 4096
  float* score_c  = S + 1316864;          // 4096
  int*   idx_h    = (int*)(S + 1320960);  // 1024
  int*   idx_w    = idx_h + 1024;         // 1024
  unsigned short* W2 = (unsigned short*)(ws + 41943040ull);
  unsigned short* W2qkv  = W2;                      // 768*256*2
  unsigned short* W2out  = W2qkv + 393216;          // 256*256*2
  unsigned short* W2comb = W2out + 131072;          // 256*512*2
  unsigned short* W2ff1  = W2comb + 262144;         // 1024*256*2
  unsigned short* W2ff2  = W2ff1 + 524288;          // 256*1024*2

  // weight splits
  k_splitW<<<(196608+255)/256, 256, 0, stream>>>(w_qkv,  W2qkv, 196608);
  k_splitW<<<(65536 +255)/256, 256, 0, stream>>>(w_out,  W2out,  65536);
  k_splitW<<<(131072+255)/256, 256, 0, stream>>>(w_comb, W2comb, 131072);
  k_splitW<<<(262144+255)/256, 256, 0, stream>>>(w_ff1,  W2ff1, 262144);
  k_splitW<<<(262144+255)/256, 256, 0, stream>>>(w_ff2,  W2ff2, 262144);

  // ---- DPSA attention branch ----
  k_chanln<<<NPOS/256, 256, 0, stream>>>(x, ln_g, ln_bb, A);
  k_splitT<<<dim3(64,4,8), 256, 0, stream>>>(A, XTa, 256, 256, 0, 0, 1);
  k_mfma<false><<<dim3(32,6,8), 256, 0, stream>>>(W2qkv, XTa, nullptr, nullptr, Q, 768, 256);
  k_l2norm<<<65536, 256, 0, stream>>>(Q, k_height);
  k_qprobe<<<2048, 256, 0, stream>>>(Q, q_probe);
  k_score<<<64, 64, 0, stream>>>(q_probe, k_height, score_r);
  k_topk<<<64, 64, 0, stream>>>(score_r, idx_h);
  k_kwidth<<<dim3(32,64), 64, 0, stream>>>(Q, idx_h, k_width);
  k_score<<<64, 64, 0, stream>>>(q_probe, k_width, score_c);
  k_topk<<<64, 64, 0, stream>>>(score_c, idx_w);
  k_gather<<<64, 256, 0, stream>>>(Q, idx_h, idx_w, kf, vf);
  k_attn<<<dim3(16,64), 256, 0, stream>>>(Q, kf, vf, A);               // out_inner -> A
  k_splitT<<<dim3(64,4,8), 256, 0, stream>>>(A, XTa, 256, 256, 0, 0, 1);
  k_mfma<false><<<dim3(32,2,8), 256, 0, stream>>>(W2out, XTa, b_out, nullptr, (float*)d_out, 256, 256);

  // ---- conv branch + combine + residual ----
  k_dw3x3<<<(Bn*256*HW)/256, 256, 0, stream>>>(x, w_dw, b_dw, Fb, 256);
  k_splitT<<<dim3(64,4,8), 256, 0, stream>>>((const float*)d_out, XT2, 256, 512, 0,   0, 1);
  k_splitT<<<dim3(64,4,8), 256, 0, stream>>>(Fb,                  XT2, 256, 512, 256, 0, 1);
  k_mfma<true><<<dim3(32,2,8), 256, 0, stream>>>(W2comb, XT2, b_comb, x, A, 256, 512); // attn_out -> A

  // ---- feedforward ----
  k_splitT<<<dim3(64,4,8), 256, 0, stream>>>(A, XTb, 256, 256, 0, 0, 1);
  k_mfma<false><<<dim3(32,8,8), 256, 0, stream>>>(W2ff1, XTb, b_ff1, nullptr, Hb, 1024, 256);
  k_ffn_fused<<<Bn*1024, 256, 0, stream>>>(Hb, w_ffdw, b_ffdw);
  // h -> XT3 transpose: STRICTLY SEQUENTIAL per batch (XT3 slot b overwrites
  // Hb slot b-1, which launch b-1 has already consumed).
  for (int b=0; b<8; ++b)
    k_splitT<<<dim3(64,16,1), 256, 0, stream>>>(Hb, XT3, 1024, 1024, 0, b, 1);
  k_mfma<false><<<dim3(32,2,8), 256, 0, stream>>>(W2ff2, XT3, b_ff2, nullptr, (float*)d_out, 256, 1024);
  k_instnorm<<<Bn*256, 256, 0, stream>>>((const float*)d_out, out);
}

// Round 5
// 1165.136 us; speedup vs baseline: 1.2050x; 1.0274x over previous
//
#include <hip/hip_runtime.h>
#include <math.h>

// Problem dims
constexpr int Bn = 8, Cd = 256, HW = 4096;
constexpr int NPOS = Bn * HW;

typedef __attribute__((ext_vector_type(8))) short bfrag;            // 8 bf16
typedef __attribute__((ext_vector_type(4))) float facc;             // 4 fp32
typedef __attribute__((ext_vector_type(8))) unsigned short us8;     // 16B store

static __device__ __forceinline__ float wredsum(float v){
  #pragma unroll
  for (int d=32; d; d>>=1) v += __shfl_xor(v,d,64);
  return v;
}
static __device__ __forceinline__ float gelu_exact(float x){
  return 0.5f*x*(1.f+erff(x*0.70710678118f));
}
// split fp32 -> bf16 hi + bf16 lo (RNE both); x ~= hi + lo with ~2^-17 rel err
static __device__ __forceinline__ void split1(float x, unsigned short& h, unsigned short& l){
  unsigned u = __float_as_uint(x);
  unsigned r = (u + 0x7FFFu + ((u>>16)&1u)) & 0xFFFF0000u;
  h = (unsigned short)(r>>16);
  float rest = x - __uint_as_float(r);
  unsigned u2 = __float_as_uint(rest);
  unsigned r2 = u2 + 0x7FFFu + ((u2>>16)&1u);
  l = (unsigned short)(r2>>16);
}

// ---------------------------------------------------------------------------
// FUSED channel-LN + split + transpose: x[b][c][p] -> XT [b]{hi[p][256],lo[p][256]}
// block: 64 px x 4 c-groups of 64c. Grid: 512.
__global__ __launch_bounds__(256) void k_lnsplit(const float* __restrict__ x,
    const float* __restrict__ g, const float* __restrict__ bb,
    unsigned short* __restrict__ xt){
  __shared__ float rs[64][5], rss[64][5];
  int pxi = threadIdx.x & 63;
  int cg  = threadIdx.x >> 6;
  int p = blockIdx.x*64 + pxi;
  int b = p >> 12, pos = p & 4095;
  const float* xb = x + ((size_t)b*Cd + cg*64)*(size_t)HW + pos;
  float s=0.f, ss=0.f;
  #pragma unroll 8
  for (int c=0;c<64;c++){ float v = xb[(size_t)c*HW]; s+=v; ss+=v*v; }
  rs[pxi][cg]=s; rss[pxi][cg]=ss;
  __syncthreads();
  s  = rs[pxi][0]+rs[pxi][1]+rs[pxi][2]+rs[pxi][3];
  ss = rss[pxi][0]+rss[pxi][1]+rss[pxi][2]+rss[pxi][3];
  float mean = s*(1.f/Cd);
  float inv  = rsqrtf(ss*(1.f/Cd) - mean*mean + 1e-5f);
  unsigned short* xh = xt + (size_t)b*2097152ull + (size_t)pos*256u + cg*64;
  unsigned short* xl = xh + 1048576u;
  for (int c0=0;c0<64;c0+=8){
    us8 hv, lv;
    #pragma unroll
    for (int j=0;j<8;j++){
      float v = xb[(size_t)(c0+j)*HW];
      v = (v-mean)*inv*g[cg*64+c0+j] + bb[cg*64+c0+j];
      unsigned short hh,ll; split1(v,hh,ll);
      hv[j]=hh; lv[j]=ll;
    }
    *(us8*)(xh + c0) = hv;
    *(us8*)(xl + c0) = lv;
  }
}

// ---------------------------------------------------------------------------
// generic split+transpose: planar fp32 [b][Cpart][4096] -> per-batch {hi[4096][Ktot], lo...}
__global__ __launch_bounds__(256) void k_splitT(const float* __restrict__ in,
    unsigned short* __restrict__ xt, int Cpart, int Ktot, int coff, int b0, int bstep){
  int b = b0 + blockIdx.z*bstep;
  int c0 = blockIdx.y*64, p0 = blockIdx.x*64;
  __shared__ float t[64][65];
  const float* ip = in + ((size_t)b*Cpart + c0)*(size_t)HW + p0;
  int tr = threadIdx.x>>4, tc4 = (threadIdx.x&15)*4;
  #pragma unroll
  for (int rr=0; rr<64; rr+=16){
    float4 v = *(const float4*)(ip + (size_t)(tr+rr)*HW + tc4);
    t[tr+rr][tc4+0]=v.x; t[tr+rr][tc4+1]=v.y; t[tr+rr][tc4+2]=v.z; t[tr+rr][tc4+3]=v.w;
  }
  __syncthreads();
  unsigned short* xh = xt + (size_t)b*2u*4096u*(size_t)Ktot + (size_t)coff + c0;
  unsigned short* xl = xh + (size_t)4096u*(size_t)Ktot;
  #pragma unroll
  for (int rr=0; rr<64; rr+=16){
    int p = tr+rr;
    ushort4 hv, lv;
    split1(t[tc4+0][p], hv.x, lv.x);
    split1(t[tc4+1][p], hv.y, lv.y);
    split1(t[tc4+2][p], hv.z, lv.z);
    split1(t[tc4+3][p], hv.w, lv.w);
    size_t off = (size_t)(p0+p)*(size_t)Ktot + tc4;
    *(ushort4*)(xh + off) = hv;
    *(ushort4*)(xl + off) = lv;
  }
}

// elementwise weight split
__global__ void k_splitW(const float* __restrict__ w, unsigned short* __restrict__ wh, int n){
  int i = blockIdx.x*256 + threadIdx.x;
  if (i<n){
    unsigned short h,l; split1(w[i],h,l);
    wh[i]=h; wh[n+i]=l;
  }
}

// ---------------------------------------------------------------------------
// MFMA GEMM: out[b][o][p] = sum_c W[o][c]*X[b][c][p] (+bias)(+resid)
// W2: hi[M*K] then lo[M*K]. Xt batch stride xbs (ushorts); lo plane at +4096*K.
template<bool RES>
__global__ __launch_bounds__(256) void k_mfma(
    const unsigned short* __restrict__ W2,
    const unsigned short* __restrict__ Xt,
    const float* __restrict__ bias, const float* __restrict__ resid,
    float* __restrict__ out, int M, int K, long xbs){
  int b  = blockIdx.z;
  int n0 = blockIdx.x*128;
  int m0 = blockIdx.y*128;
  int wave = threadIdx.x>>6, lane = threadIdx.x&63;
  int wm = (wave>>1)*64, wn = (wave&1)*64;
  int l15 = lane&15, half = lane>>4;
  const unsigned short* Wh = W2;
  const unsigned short* Wl = W2 + (size_t)M*K;
  const unsigned short* Xh = Xt + (size_t)b*(size_t)xbs;
  const unsigned short* Xl = Xh + (size_t)4096u*(size_t)K;

  facc acc[4][4];
  #pragma unroll
  for (int i=0;i<4;i++)
    #pragma unroll
    for (int j=0;j<4;j++) acc[i][j] = (facc){0.f,0.f,0.f,0.f};

  const size_t wrow[4] = {
    (size_t)(m0+wm+ 0+l15)*(size_t)K, (size_t)(m0+wm+16+l15)*(size_t)K,
    (size_t)(m0+wm+32+l15)*(size_t)K, (size_t)(m0+wm+48+l15)*(size_t)K };
  const size_t xrow[4] = {
    (size_t)(n0+wn+ 0+l15)*(size_t)K, (size_t)(n0+wn+16+l15)*(size_t)K,
    (size_t)(n0+wn+32+l15)*(size_t)K, (size_t)(n0+wn+48+l15)*(size_t)K };

  for (int k0=0; k0<K; k0+=32){
    int ks = k0 + half*8;
    bfrag ah[4], al[4], bh[4], bl[4];
    #pragma unroll
    for (int i=0;i<4;i++){
      ah[i] = *(const bfrag*)(Wh + wrow[i] + ks);
      al[i] = *(const bfrag*)(Wl + wrow[i] + ks);
      bh[i] = *(const bfrag*)(Xh + xrow[i] + ks);
      bl[i] = *(const bfrag*)(Xl + xrow[i] + ks);
    }
    #pragma unroll
    for (int i=0;i<4;i++)
      #pragma unroll
      for (int j=0;j<4;j++){
        acc[i][j] = __builtin_amdgcn_mfma_f32_16x16x32_bf16(ah[i], bh[j], acc[i][j],0,0,0);
        acc[i][j] = __builtin_amdgcn_mfma_f32_16x16x32_bf16(ah[i], bl[j], acc[i][j],0,0,0);
        acc[i][j] = __builtin_amdgcn_mfma_f32_16x16x32_bf16(al[i], bh[j], acc[i][j],0,0,0);
      }
  }
  #pragma unroll
  for (int i=0;i<4;i++){
    int o = m0+wm+i*16+half*4;
    #pragma unroll
    for (int j=0;j<4;j++){
      int p = n0+wn+j*16+l15;
      size_t ob = ((size_t)b*M + o)*(size_t)HW + p;
      #pragma unroll
      for (int r=0;r<4;r++){
        float v = acc[i][j][r];
        if (bias) v += bias[o+r];
        if (RES)  v += resid[ob + (size_t)r*HW];
        out[ob + (size_t)r*HW] = v;
      }
    }
  }
}

// ---------------------------------------------------------------------------
// l2norm along W for q & k rows (in-place on Q); writes k_height rowsums for k.
__global__ __launch_bounds__(256) void k_l2norm(float* __restrict__ qkv,
    float* __restrict__ k_height){
  int row  = blockIdx.x*4 + (threadIdx.x>>6);
  int lane = threadIdx.x & 63;
  int part = row >> 17;
  int rem  = row & 131071;
  int Bp   = rem >> 11;
  int c    = (rem >> 6) & 31;
  int h    = rem & 63;
  int b = Bp>>3, hd = Bp&7;
  float* ptr = qkv + ((size_t)b*768 + part*256 + hd*32 + c)*(size_t)HW + h*64;
  float v = ptr[lane];
  float ss = v*v, sv = v;
  #pragma unroll
  for (int d=32; d; d>>=1){ ss += __shfl_xor(ss,d,64); sv += __shfl_xor(sv,d,64); }
  float inv = 1.f / fmaxf(sqrtf(ss), 1e-12f);
  ptr[lane] = v*inv;
  if (lane==0 && part) k_height[(size_t)Bp*2048 + c*64 + h] = sv*inv;
}

__global__ __launch_bounds__(256) void k_qprobe(const float* __restrict__ qkv,
    float* __restrict__ q_probe){
  int Bp = blockIdx.x >> 5;
  int c  = blockIdx.x & 31;
  int b = Bp>>3, hd = Bp&7;
  const float* qp = qkv + ((size_t)b*768 + hd*32 + c)*(size_t)HW;
  float s = 0.f;
  for (int i=threadIdx.x*4; i<HW; i+=1024){
    float4 v = *(const float4*)(qp+i);
    s += v.x+v.y+v.z+v.w;
  }
  s = wredsum(s);
  __shared__ float red[4];
  if ((threadIdx.x&63)==0) red[threadIdx.x>>6] = s;
  __syncthreads();
  if (threadIdx.x==0) q_probe[blockIdx.x] = red[0]+red[1]+red[2]+red[3];
}

__global__ void k_score(const float* __restrict__ q_probe,
    const float* __restrict__ agg, float* __restrict__ score){
  int Bp = blockIdx.x; int t = threadIdx.x;
  float s = 0.f;
  for (int c=0;c<32;c++) s += q_probe[Bp*32+c] * agg[(size_t)Bp*2048 + c*64 + t];
  score[Bp*64+t] = s;
}

__global__ void k_topk(const float* __restrict__ score, int* __restrict__ idx){
  int Bp = blockIdx.x; int lane = threadIdx.x;
  float v = score[Bp*64+lane];
  for (int it=0; it<16; ++it){
    float m = v;
    #pragma unroll
    for (int d=32; d; d>>=1) m = fmaxf(m, __shfl_xor(m,d,64));
    unsigned long long mask = __ballot(v==m);
    int sel = __ffsll((unsigned long long)mask) - 1;
    if (lane==0) idx[Bp*16+it] = sel;
    if (lane==sel) v = -3.0e38f;
  }
}

__global__ void k_kwidth(const float* __restrict__ qkv, const int* __restrict__ idx_h,
    float* __restrict__ k_width){
  int c = blockIdx.x, Bp = blockIdx.y, w = threadIdx.x;
  int b = Bp>>3, hd = Bp&7;
  const float* kp = qkv + ((size_t)b*768 + 256 + hd*32 + c)*(size_t)HW;
  float s = 0.f;
  for (int i=0;i<16;i++) s += kp[idx_h[Bp*16+i]*64 + w];
  k_width[(size_t)Bp*2048 + c*64 + w] = s;
}

__global__ __launch_bounds__(256) void k_gather(const float* __restrict__ qkv,
    const int* __restrict__ idx_h, const int* __restrict__ idx_w,
    float* __restrict__ kf, float* __restrict__ vf){
  int Bp = blockIdx.x; int b = Bp>>3, hd = Bp&7;
  __shared__ int hi[16], wj[16];
  if (threadIdx.x < 16) hi[threadIdx.x] = idx_h[Bp*16+threadIdx.x];
  else if (threadIdx.x < 32) wj[threadIdx.x-16] = idx_w[Bp*16+threadIdx.x-16];
  __syncthreads();
  const size_t base = ((size_t)b*768 + hd*32)*(size_t)HW;
  for (int e=threadIdx.x; e<8192; e+=256){
    int c = e & 31, pair = e >> 5;
    int i = pair >> 4, j = pair & 15;
    int pos = hi[i]*64 + wj[j];
    kf[(size_t)Bp*8192 + e] = qkv[base + (size_t)(256+c)*HW + pos];
    vf[(size_t)Bp*8192 + e] = qkv[base + (size_t)(512+c)*HW + pos];
  }
}

// attention, fixed-range softmax (|s|<=32 since q,k l2-normalized => no max
// tracking needed; exp(s)<=8e13, sums<=2e16 all in fp32 range).
// Writes transposed bf16 hi/lo GEMM input directly (into dead v-planes).
__global__ __launch_bounds__(256) void k_attn(const float* __restrict__ qkv,
    const float* __restrict__ kf, const float* __restrict__ vf,
    unsigned short* __restrict__ xout){
  __shared__ float lk[8192];
  __shared__ float lv2[8192];
  int Bp = blockIdx.y, pt = blockIdx.x;
  int b = Bp>>3, hd = Bp&7;
  for (int e=threadIdx.x; e<8192; e+=256){
    lk[e]  = kf[(size_t)Bp*8192 + e];
    lv2[e] = vf[(size_t)Bp*8192 + e];
  }
  __syncthreads();
  int p = pt*256 + threadIdx.x;
  const float* qb = qkv + ((size_t)b*768 + hd*32)*(size_t)HW + p;
  float qr[32];
  #pragma unroll
  for (int c=0;c<32;c++) qr[c] = qb[(size_t)c*HW];
  float l = 0.f;
  float acc[32];
  #pragma unroll
  for (int c=0;c<32;c++) acc[c] = 0.f;
  for (int j=0;j<256;j++){
    const float4* krow = (const float4*)&lk[j*32];
    float s = 0.f;
    #pragma unroll
    for (int c4=0;c4<8;c4++){
      float4 kv = krow[c4];
      s += qr[c4*4+0]*kv.x + qr[c4*4+1]*kv.y + qr[c4*4+2]*kv.z + qr[c4*4+3]*kv.w;
    }
    float pe = __expf(s);
    l += pe;
    const float4* vrow = (const float4*)&lv2[j*32];
    #pragma unroll
    for (int c4=0;c4<8;c4++){
      float4 vv = vrow[c4];
      acc[c4*4+0] += pe*vv.x;
      acc[c4*4+1] += pe*vv.y;
      acc[c4*4+2] += pe*vv.z;
      acc[c4*4+3] += pe*vv.w;
    }
  }
  float invl = 1.f/l;
  unsigned short* uX = xout + (size_t)b*6291456ull;
  #pragma unroll
  for (int c0=0;c0<32;c0+=8){
    us8 hv, lv3;
    #pragma unroll
    for (int j=0;j<8;j++){
      unsigned short hh,ll; split1(acc[c0+j]*invl, hh, ll);
      hv[j]=hh; lv3[j]=ll;
    }
    *(us8*)(uX + (size_t)p*256u + hd*32 + c0) = hv;
    *(us8*)(uX + 1048576u + (size_t)p*256u + hd*32 + c0) = lv3;
  }
}

// ---------------------------------------------------------------------------
// FUSED depthwise 3x3 + split + transpose into XT2 at coff=256 (Ktot=512).
// Grid (128, 4): thread=pixel, blockIdx.y = 64-channel group.
__global__ __launch_bounds__(256) void k_dwsplit(const float* __restrict__ x,
    const float* __restrict__ w, const float* __restrict__ bias,
    unsigned short* __restrict__ xt){
  int p = blockIdx.x*256 + threadIdx.x;
  int b = p >> 12, pos = p & 4095;
  int h = pos>>6, wx = pos&63;
  int c0 = blockIdx.y*64;
  unsigned short* xh = xt + (size_t)b*4194304ull + (size_t)pos*512u + 256u + c0;
  unsigned short* xl = xh + 2097152u;
  for (int cc=0; cc<64; cc+=8){
    us8 hv, lv;
    #pragma unroll
    for (int j=0;j<8;j++){
      int c = c0+cc+j;
      const float* ip = x + ((size_t)b*Cd + c)*(size_t)HW;
      const float* wp = w + c*9;
      float s = bias[c];
      #pragma unroll
      for (int kh=-1; kh<=1; ++kh){
        int hh = h+kh; if ((unsigned)hh >= 64u) continue;
        #pragma unroll
        for (int kw=-1; kw<=1; ++kw){
          int ww2 = wx+kw; if ((unsigned)ww2 >= 64u) continue;
          s += wp[(kh+1)*3 + (kw+1)] * ip[hh*64 + ww2];
        }
      }
      unsigned short hh2,ll2; split1(s,hh2,ll2);
      hv[j]=hh2; lv[j]=ll2;
    }
    *(us8*)(xh+cc) = hv;
    *(us8*)(xl+cc) = lv;
  }
}

// ---------------------------------------------------------------------------
__global__ __launch_bounds__(256) void k_ffn_fused(float* __restrict__ h,
    const float* __restrict__ wdw, const float* __restrict__ bdw){
  __shared__ float lds[4096];
  __shared__ float red[8];
  int plane = blockIdx.x;
  int c = plane & 1023;
  float* hp = h + (size_t)plane*(size_t)HW;
  int t = threadIdx.x;
  int wid = t>>6, lane = t&63;

  float4 v[4];
  float s=0.f, ss=0.f;
  #pragma unroll
  for (int k2=0;k2<4;k2++){
    v[k2] = *(const float4*)(hp + k2*1024 + t*4);
    s  += v[k2].x+v[k2].y+v[k2].z+v[k2].w;
    ss += v[k2].x*v[k2].x+v[k2].y*v[k2].y+v[k2].z*v[k2].z+v[k2].w*v[k2].w;
  }
  s = wredsum(s); ss = wredsum(ss);
  if (lane==0){ red[wid]=s; red[4+wid]=ss; }
  __syncthreads();
  s  = red[0]+red[1]+red[2]+red[3];
  ss = red[4]+red[5]+red[6]+red[7];
  float mean = s*(1.f/HW);
  float inv  = rsqrtf(ss*(1.f/HW) - mean*mean + 1e-5f);

  #pragma unroll
  for (int k2=0;k2<4;k2++){
    int i = k2*1024 + t*4;
    lds[i+0] = gelu_exact((v[k2].x-mean)*inv);
    lds[i+1] = gelu_exact((v[k2].y-mean)*inv);
    lds[i+2] = gelu_exact((v[k2].z-mean)*inv);
    lds[i+3] = gelu_exact((v[k2].w-mean)*inv);
  }
  __syncthreads();

  float w9[9];
  #pragma unroll
  for (int i=0;i<9;i++) w9[i] = wdw[c*9+i];
  float bv = bdw[c];
  float r[16];
  float s2=0.f, ss2=0.f;
  #pragma unroll
  for (int k2=0;k2<4;k2++){
    #pragma unroll
    for (int j=0;j<4;j++){
      int px = k2*1024 + t*4 + j;
      int hh = px>>6, ww = px&63;
      float acc = bv;
      #pragma unroll
      for (int kh=-1; kh<=1; ++kh){
        int h2 = hh+kh; if ((unsigned)h2 >= 64u) continue;
        #pragma unroll
        for (int kw=-1; kw<=1; ++kw){
          int w2 = ww+kw; if ((unsigned)w2 >= 64u) continue;
          acc += w9[(kh+1)*3+(kw+1)] * lds[h2*64 + w2];
        }
      }
      r[k2*4+j] = acc;
      s2 += acc; ss2 += acc*acc;
    }
  }
  s2 = wredsum(s2); ss2 = wredsum(ss2);
  __syncthreads();
  if (lane==0){ red[wid]=s2; red[4+wid]=ss2; }
  __syncthreads();
  s2  = red[0]+red[1]+red[2]+red[3];
  ss2 = red[4]+red[5]+red[6]+red[7];
  float mean2 = s2*(1.f/HW);
  float inv2  = rsqrtf(ss2*(1.f/HW) - mean2*mean2 + 1e-5f);

  #pragma unroll
  for (int k2=0;k2<4;k2++){
    int i = k2*1024 + t*4;
    float4 o;
    o.x = lds[i+0] + gelu_exact((r[k2*4+0]-mean2)*inv2);
    o.y = lds[i+1] + gelu_exact((r[k2*4+1]-mean2)*inv2);
    o.z = lds[i+2] + gelu_exact((r[k2*4+2]-mean2)*inv2);
    o.w = lds[i+3] + gelu_exact((r[k2*4+3]-mean2)*inv2);
    *(float4*)(hp + i) = o;
  }
}

// instance norm over HW per plane; in-place safe
__global__ __launch_bounds__(256) void k_instnorm(const float* __restrict__ in,
    float* __restrict__ out){
  size_t base = (size_t)blockIdx.x * HW;
  const float* p = in + base;
  float s=0.f, ss=0.f;
  for (int i=threadIdx.x*4; i<HW; i+=1024){
    float4 v = *(const float4*)(p+i);
    s  += v.x+v.y+v.z+v.w;
    ss += v.x*v.x+v.y*v.y+v.z*v.z+v.w*v.w;
  }
  s = wredsum(s); ss = wredsum(ss);
  __shared__ float sh[8];
  int wid = threadIdx.x>>6;
  if ((threadIdx.x&63)==0){ sh[wid]=s; sh[4+wid]=ss; }
  __syncthreads();
  s  = sh[0]+sh[1]+sh[2]+sh[3];
  ss = sh[4]+sh[5]+sh[6]+sh[7];
  float mean = s*(1.f/HW);
  float inv  = rsqrtf(ss*(1.f/HW) - mean*mean + 1e-5f);
  for (int i=threadIdx.x*4; i<HW; i+=1024){
    float4 v = *(const float4*)(p+i);
    float4 r;
    r.x = (v.x-mean)*inv; r.y = (v.y-mean)*inv; r.z = (v.z-mean)*inv; r.w = (v.w-mean)*inv;
    *(float4*)(out + base + i) = r;
  }
}

// ---------------------------------------------------------------------------
extern "C" void kernel_launch(void* const* d_in, const int* in_sizes, int n_in,
                              void* d_out, int out_size, void* d_ws, size_t ws_size,
                              hipStream_t stream){
  const float* x      = (const float*)d_in[0];
  const float* ln_g   = (const float*)d_in[1];
  const float* ln_bb  = (const float*)d_in[2];
  const float* w_qkv  = (const float*)d_in[3];
  const float* w_out  = (const float*)d_in[4];
  const float* b_out  = (const float*)d_in[5];
  const float* w_dw   = (const float*)d_in[6];
  const float* b_dw   = (const float*)d_in[7];
  const float* w_comb = (const float*)d_in[8];
  const float* b_comb = (const float*)d_in[9];
  const float* w_ff1  = (const float*)d_in[10];
  const float* b_ff1  = (const float*)d_in[11];
  const float* w_ffdw = (const float*)d_in[12];
  const float* b_ffdw = (const float*)d_in[13];
  const float* w_ff2  = (const float*)d_in[14];
  const float* b_ff2  = (const float*)d_in[15];
  float* out = (float*)d_out;
  float* ws  = (float*)d_ws;

  // ---- workspace (floats), total 42,860,544 = 163.5 MiB ----
  // [0, 1.33M):   attention smalls (dead before comb GEMM writes A)
  // [0, 8.39M):   A (attn_out fp32, written by comb GEMM)
  // [8.39M,33.55M): Q qkv (q/k planes; v-planes reused as w_out GEMM input)
  // [16.77M,33.55M): XT2 comb-input (after v-planes consumed)
  // [33.55M,41.94M): XTa (LN'ed x, bf16 transposed)
  // [8.39M,41.94M): Hb (ff1 out), XT3 ping-pong at [4.19M,37.75M)
  // d_out: w_out result -> XTb (ff1 input) -> ff2 result -> final
  // [41.94M,42.86M): W2 weight splits
  float* A   = ws;
  float* Q   = ws + 8388608ull;
  float* Hb  = ws + 8388608ull;
  unsigned short* XT3 = (unsigned short*)(ws + 4194304ull);
  unsigned short* XT2 = (unsigned short*)(ws + 16777216ull);
  unsigned short* XTa = (unsigned short*)(ws + 33554432ull);
  unsigned short* XTb = (unsigned short*)d_out;
  unsigned short* Xattn = (unsigned short*)(Q + 2097152ull);   // v-plane of batch 0
  float* S = ws;
  float* kf       = S;                    // 524288
  float* vf       = S + 524288;           // 524288
  float* k_height = S + 1048576;          // 131072
  float* k_width  = S + 1179648;          // 131072
  float* q_probe  = S + 1310720;          // 2048
  float* score_r  = S + 1312768;          // 4096
  float* score_c  = S + 1316864;          // 4096
  int*   idx_h    = (int*)(S + 1320960);  // 1024
  int*   idx_w    = idx_h + 1024;         // 1024
  unsigned short* W2 = (unsigned short*)(ws + 41943040ull);
  unsigned short* W2qkv  = W2;
  unsigned short* W2out  = W2qkv + 393216;
  unsigned short* W2comb = W2out + 131072;
  unsigned short* W2ff1  = W2comb + 262144;
  unsigned short* W2ff2  = W2ff1 + 524288;

  // weight splits
  k_splitW<<<(196608+255)/256, 256, 0, stream>>>(w_qkv,  W2qkv, 196608);
  k_splitW<<<(65536 +255)/256, 256, 0, stream>>>(w_out,  W2out,  65536);
  k_splitW<<<(131072+255)/256, 256, 0, stream>>>(w_comb, W2comb, 131072);
  k_splitW<<<(262144+255)/256, 256, 0, stream>>>(w_ff1,  W2ff1, 262144);
  k_splitW<<<(262144+255)/256, 256, 0, stream>>>(w_ff2,  W2ff2, 262144);

  // ---- DPSA attention branch ----
  k_lnsplit<<<512, 256, 0, stream>>>(x, ln_g, ln_bb, XTa);
  k_mfma<false><<<dim3(32,6,8), 256, 0, stream>>>(W2qkv, XTa, nullptr, nullptr, Q, 768, 256, 2097152);
  k_l2norm<<<65536, 256, 0, stream>>>(Q, k_height);
  k_qprobe<<<2048, 256, 0, stream>>>(Q, q_probe);
  k_score<<<64, 64, 0, stream>>>(q_probe, k_height, score_r);
  k_topk<<<64, 64, 0, stream>>>(score_r, idx_h);
  k_kwidth<<<dim3(32,64), 64, 0, stream>>>(Q, idx_h, k_width);
  k_score<<<64, 64, 0, stream>>>(q_probe, k_width, score_c);
  k_topk<<<64, 64, 0, stream>>>(score_c, idx_w);
  k_gather<<<64, 256, 0, stream>>>(Q, idx_h, idx_w, kf, vf);
  k_attn<<<dim3(16,64), 256, 0, stream>>>(Q, kf, vf, Xattn);     // -> v-planes (bf16 T)
  k_mfma<false><<<dim3(32,2,8), 256, 0, stream>>>(W2out, Xattn, b_out, nullptr, (float*)d_out, 256, 256, 6291456);

  // ---- conv branch + combine + residual ----
  k_splitT<<<dim3(64,4,8), 256, 0, stream>>>((const float*)d_out, XT2, 256, 512, 0, 0, 1);
  k_dwsplit<<<dim3(128,4), 256, 0, stream>>>(x, w_dw, b_dw, XT2);
  k_mfma<true><<<dim3(32,2,8), 256, 0, stream>>>(W2comb, XT2, b_comb, x, A, 256, 512, 4194304);

  // ---- feedforward ----
  k_splitT<<<dim3(64,4,8), 256, 0, stream>>>(A, XTb, 256, 256, 0, 0, 1);
  k_mfma<false><<<dim3(32,8,8), 256, 0, stream>>>(W2ff1, XTb, b_ff1, nullptr, Hb, 1024, 256, 2097152);
  k_ffn_fused<<<Bn*1024, 256, 0, stream>>>(Hb, w_ffdw, b_ffdw);
  for (int b=0; b<8; ++b)   // XT3 slot b overwrites Hb slot b-1: strictly sequential
    k_splitT<<<dim3(64,16,1), 256, 0, stream>>>(Hb, XT3, 1024, 1024, 0, b, 1);
  k_mfma<false><<<dim3(32,2,8), 256, 0, stream>>>(W2ff2, XT3, b_ff2, nullptr, (float*)d_out, 256, 1024, 8388608);
  k_instnorm<<<Bn*256, 256, 0, stream>>>((const float*)d_out, out);
}

// Round 6
// 864.837 us; speedup vs baseline: 1.6234x; 1.3472x over previous
//
#include <hip/hip_runtime.h>
#include <math.h>

// Problem dims
constexpr int Bn = 8, Cd = 256, HW = 4096;
constexpr int NPOS = Bn * HW;

typedef __attribute__((ext_vector_type(8))) short bfrag;            // 8 bf16
typedef __attribute__((ext_vector_type(4))) float facc;             // 4 fp32
typedef __attribute__((ext_vector_type(8))) unsigned short us8;     // 16B

static __device__ __forceinline__ float wredsum(float v){
  #pragma unroll
  for (int d=32; d; d>>=1) v += __shfl_xor(v,d,64);
  return v;
}
static __device__ __forceinline__ float gelu_exact(float x){
  return 0.5f*x*(1.f+erff(x*0.70710678118f));
}
static __device__ __forceinline__ unsigned short bf16r(float x){
  unsigned u = __float_as_uint(x);
  u += 0x7FFFu + ((u>>16)&1u);
  return (unsigned short)(u>>16);
}
// split fp32 -> bf16 hi + bf16 lo
static __device__ __forceinline__ void split1(float x, unsigned short& h, unsigned short& l){
  unsigned u = __float_as_uint(x);
  unsigned r = (u + 0x7FFFu + ((u>>16)&1u)) & 0xFFFF0000u;
  h = (unsigned short)(r>>16);
  float rest = x - __uint_as_float(r);
  unsigned u2 = __float_as_uint(rest);
  unsigned r2 = u2 + 0x7FFFu + ((u2>>16)&1u);
  l = (unsigned short)(r2>>16);
}

// ---------------------------------------------------------------------------
// FUSED channel-LN + split + transpose: x -> XTa [b]{hi[4096][256],lo[4096][256]}
__global__ __launch_bounds__(256) void k_lnsplit(const float* __restrict__ x,
    const float* __restrict__ g, const float* __restrict__ bb,
    unsigned short* __restrict__ xt){
  __shared__ float rs[64][5], rss[64][5];
  int pxi = threadIdx.x & 63;
  int cg  = threadIdx.x >> 6;
  int p = blockIdx.x*64 + pxi;
  int b = p >> 12, pos = p & 4095;
  const float* xb = x + ((size_t)b*Cd + cg*64)*(size_t)HW + pos;
  float s=0.f, ss=0.f;
  #pragma unroll 8
  for (int c=0;c<64;c++){ float v = xb[(size_t)c*HW]; s+=v; ss+=v*v; }
  rs[pxi][cg]=s; rss[pxi][cg]=ss;
  __syncthreads();
  s  = rs[pxi][0]+rs[pxi][1]+rs[pxi][2]+rs[pxi][3];
  ss = rss[pxi][0]+rss[pxi][1]+rss[pxi][2]+rss[pxi][3];
  float mean = s*(1.f/Cd);
  float inv  = rsqrtf(ss*(1.f/Cd) - mean*mean + 1e-5f);
  unsigned short* xh = xt + (size_t)b*2097152ull + (size_t)pos*256u + cg*64;
  unsigned short* xl = xh + 1048576u;
  for (int c0=0;c0<64;c0+=8){
    us8 hv, lv;
    #pragma unroll
    for (int j=0;j<8;j++){
      float v = xb[(size_t)(c0+j)*HW];
      v = (v-mean)*inv*g[cg*64+c0+j] + bb[cg*64+c0+j];
      unsigned short hh,ll; split1(v,hh,ll);
      hv[j]=hh; lv[j]=ll;
    }
    *(us8*)(xh + c0) = hv;
    *(us8*)(xl + c0) = lv;
  }
}

// weight split (qkv only)
__global__ void k_splitW(const float* __restrict__ w, unsigned short* __restrict__ wh, int n){
  int i = blockIdx.x*256 + threadIdx.x;
  if (i<n){
    unsigned short h,l; split1(w[i],h,l);
    wh[i]=h; wh[n+i]=l;
  }
}
// plain weight convert
__global__ void k_cvtW(const float* __restrict__ w, unsigned short* __restrict__ wb, int n){
  int i = blockIdx.x*256 + threadIdx.x;
  if (i<n) wb[i] = bf16r(w[i]);
}

// ---------------------------------------------------------------------------
// 3-term split MFMA GEMM (qkv only)
__global__ __launch_bounds__(256) void k_mfma3(
    const unsigned short* __restrict__ W2,
    const unsigned short* __restrict__ Xt,
    float* __restrict__ out, int M, int K, long xbs){
  int b  = blockIdx.z;
  int n0 = blockIdx.x*128;
  int m0 = blockIdx.y*128;
  int wave = threadIdx.x>>6, lane = threadIdx.x&63;
  int wm = (wave>>1)*64, wn = (wave&1)*64;
  int l15 = lane&15, half = lane>>4;
  const unsigned short* Wh = W2;
  const unsigned short* Wl = W2 + (size_t)M*K;
  const unsigned short* Xh = Xt + (size_t)b*(size_t)xbs;
  const unsigned short* Xl = Xh + (size_t)4096u*(size_t)K;

  facc acc[4][4];
  #pragma unroll
  for (int i=0;i<4;i++)
    #pragma unroll
    for (int j=0;j<4;j++) acc[i][j] = (facc){0.f,0.f,0.f,0.f};

  const size_t wrow[4] = {
    (size_t)(m0+wm+ 0+l15)*(size_t)K, (size_t)(m0+wm+16+l15)*(size_t)K,
    (size_t)(m0+wm+32+l15)*(size_t)K, (size_t)(m0+wm+48+l15)*(size_t)K };
  const size_t xrow[4] = {
    (size_t)(n0+wn+ 0+l15)*(size_t)K, (size_t)(n0+wn+16+l15)*(size_t)K,
    (size_t)(n0+wn+32+l15)*(size_t)K, (size_t)(n0+wn+48+l15)*(size_t)K };

  for (int k0=0; k0<K; k0+=32){
    int ks = k0 + half*8;
    bfrag ah[4], al[4], bh[4], bl[4];
    #pragma unroll
    for (int i=0;i<4;i++){
      ah[i] = *(const bfrag*)(Wh + wrow[i] + ks);
      al[i] = *(const bfrag*)(Wl + wrow[i] + ks);
      bh[i] = *(const bfrag*)(Xh + xrow[i] + ks);
      bl[i] = *(const bfrag*)(Xl + xrow[i] + ks);
    }
    #pragma unroll
    for (int i=0;i<4;i++)
      #pragma unroll
      for (int j=0;j<4;j++){
        acc[i][j] = __builtin_amdgcn_mfma_f32_16x16x32_bf16(ah[i], bh[j], acc[i][j],0,0,0);
        acc[i][j] = __builtin_amdgcn_mfma_f32_16x16x32_bf16(ah[i], bl[j], acc[i][j],0,0,0);
        acc[i][j] = __builtin_amdgcn_mfma_f32_16x16x32_bf16(al[i], bh[j], acc[i][j],0,0,0);
      }
  }
  #pragma unroll
  for (int i=0;i<4;i++){
    int o = m0+wm+i*16+half*4;
    #pragma unroll
    for (int j=0;j<4;j++){
      int p = n0+wn+j*16+l15;
      size_t ob = ((size_t)b*M + o)*(size_t)HW + p;
      #pragma unroll
      for (int r=0;r<4;r++)
        out[ob + (size_t)r*HW] = acc[i][j][r];
    }
  }
}

// ---------------------------------------------------------------------------
// plain bf16 MFMA GEMM
template<bool RES>
__global__ __launch_bounds__(256) void k_mfma1(
    const unsigned short* __restrict__ Wb,
    const unsigned short* __restrict__ Xt,
    const float* __restrict__ bias, const float* __restrict__ resid,
    float* __restrict__ out, int M, int K, long xbs){
  int b  = blockIdx.z;
  int n0 = blockIdx.x*128;
  int m0 = blockIdx.y*128;
  int wave = threadIdx.x>>6, lane = threadIdx.x&63;
  int wm = (wave>>1)*64, wn = (wave&1)*64;
  int l15 = lane&15, half = lane>>4;
  const unsigned short* Xh = Xt + (size_t)b*(size_t)xbs;

  facc acc[4][4];
  #pragma unroll
  for (int i=0;i<4;i++)
    #pragma unroll
    for (int j=0;j<4;j++) acc[i][j] = (facc){0.f,0.f,0.f,0.f};

  const size_t wrow[4] = {
    (size_t)(m0+wm+ 0+l15)*(size_t)K, (size_t)(m0+wm+16+l15)*(size_t)K,
    (size_t)(m0+wm+32+l15)*(size_t)K, (size_t)(m0+wm+48+l15)*(size_t)K };
  const size_t xrow[4] = {
    (size_t)(n0+wn+ 0+l15)*(size_t)K, (size_t)(n0+wn+16+l15)*(size_t)K,
    (size_t)(n0+wn+32+l15)*(size_t)K, (size_t)(n0+wn+48+l15)*(size_t)K };

  #pragma unroll 2
  for (int k0=0; k0<K; k0+=32){
    int ks = k0 + half*8;
    bfrag ah[4], bh[4];
    #pragma unroll
    for (int i=0;i<4;i++){
      ah[i] = *(const bfrag*)(Wb + wrow[i] + ks);
      bh[i] = *(const bfrag*)(Xh + xrow[i] + ks);
    }
    #pragma unroll
    for (int i=0;i<4;i++)
      #pragma unroll
      for (int j=0;j<4;j++)
        acc[i][j] = __builtin_amdgcn_mfma_f32_16x16x32_bf16(ah[i], bh[j], acc[i][j],0,0,0);
  }
  #pragma unroll
  for (int i=0;i<4;i++){
    int o = m0+wm+i*16+half*4;
    #pragma unroll
    for (int j=0;j<4;j++){
      int p = n0+wn+j*16+l15;
      size_t ob = ((size_t)b*M + o)*(size_t)HW + p;
      #pragma unroll
      for (int r=0;r<4;r++){
        float v = acc[i][j][r];
        if (bias) v += bias[o+r];
        if (RES)  v += resid[ob + (size_t)r*HW];
        out[ob + (size_t)r*HW] = v;
      }
    }
  }
}

// ---------------------------------------------------------------------------
// l2norm along W for q & k rows (in-place); writes k_height rowsums for k.
__global__ __launch_bounds__(256) void k_l2norm(float* __restrict__ qkv,
    float* __restrict__ k_height){
  int row  = blockIdx.x*4 + (threadIdx.x>>6);
  int lane = threadIdx.x & 63;
  int part = row >> 17;
  int rem  = row & 131071;
  int Bp   = rem >> 11;
  int c    = (rem >> 6) & 31;
  int h    = rem & 63;
  int b = Bp>>3, hd = Bp&7;
  float* ptr = qkv + ((size_t)b*768 + part*256 + hd*32 + c)*(size_t)HW + h*64;
  float v = ptr[lane];
  float ss = v*v, sv = v;
  #pragma unroll
  for (int d=32; d; d>>=1){ ss += __shfl_xor(ss,d,64); sv += __shfl_xor(sv,d,64); }
  float inv = 1.f / fmaxf(sqrtf(ss), 1e-12f);
  ptr[lane] = v*inv;
  if (lane==0 && part) k_height[(size_t)Bp*2048 + c*64 + h] = sv*inv;
}

// Q fp32 planar -> QT [Bp][4096][32] bf16 (post-l2norm)
__global__ __launch_bounds__(256) void k_qT(const float* __restrict__ qkv,
    unsigned short* __restrict__ qt){
  __shared__ float t[64][33];
  int Bp = blockIdx.y, p0 = blockIdx.x*64;
  int b = Bp>>3, hd = Bp&7;
  const float* qp = qkv + ((size_t)b*768 + hd*32)*(size_t)HW + p0;
  int c8 = threadIdx.x>>6, px = threadIdx.x&63;
  #pragma unroll
  for (int j=0;j<8;j++)
    t[px][c8*8+j] = qp[(size_t)(c8*8+j)*HW + px];
  __syncthreads();
  int px2 = threadIdx.x>>2, ch = threadIdx.x&3;
  us8 hv;
  #pragma unroll
  for (int j=0;j<8;j++) hv[j] = bf16r(t[px2][ch*8+j]);
  *(us8*)(qt + ((size_t)Bp*4096 + p0 + px2)*32 + ch*8) = hv;
}

__global__ __launch_bounds__(256) void k_qprobe(const float* __restrict__ qkv,
    float* __restrict__ q_probe){
  int Bp = blockIdx.x >> 5;
  int c  = blockIdx.x & 31;
  int b = Bp>>3, hd = Bp&7;
  const float* qp = qkv + ((size_t)b*768 + hd*32 + c)*(size_t)HW;
  float s = 0.f;
  for (int i=threadIdx.x*4; i<HW; i+=1024){
    float4 v = *(const float4*)(qp+i);
    s += v.x+v.y+v.z+v.w;
  }
  s = wredsum(s);
  __shared__ float red[4];
  if ((threadIdx.x&63)==0) red[threadIdx.x>>6] = s;
  __syncthreads();
  if (threadIdx.x==0) q_probe[blockIdx.x] = red[0]+red[1]+red[2]+red[3];
}

__global__ void k_score(const float* __restrict__ q_probe,
    const float* __restrict__ agg, float* __restrict__ score){
  int Bp = blockIdx.x; int t = threadIdx.x;
  float s = 0.f;
  for (int c=0;c<32;c++) s += q_probe[Bp*32+c] * agg[(size_t)Bp*2048 + c*64 + t];
  score[Bp*64+t] = s;
}

__global__ void k_topk(const float* __restrict__ score, int* __restrict__ idx){
  int Bp = blockIdx.x; int lane = threadIdx.x;
  float v = score[Bp*64+lane];
  for (int it=0; it<16; ++it){
    float m = v;
    #pragma unroll
    for (int d=32; d; d>>=1) m = fmaxf(m, __shfl_xor(m,d,64));
    unsigned long long mask = __ballot(v==m);
    int sel = __ffsll((unsigned long long)mask) - 1;
    if (lane==0) idx[Bp*16+it] = sel;
    if (lane==sel) v = -3.0e38f;
  }
}

__global__ void k_kwidth(const float* __restrict__ qkv, const int* __restrict__ idx_h,
    float* __restrict__ k_width){
  int c = blockIdx.x, Bp = blockIdx.y, w = threadIdx.x;
  int b = Bp>>3, hd = Bp&7;
  const float* kp = qkv + ((size_t)b*768 + 256 + hd*32 + c)*(size_t)HW;
  float s = 0.f;
  for (int i=0;i<16;i++) s += kp[idx_h[Bp*16+i]*64 + w];
  k_width[(size_t)Bp*2048 + c*64 + w] = s;
}

// gather selected K [Bp][256][32] bf16 and V^T [Bp][32][256] bf16
__global__ __launch_bounds__(256) void k_gather_bf(const float* __restrict__ qkv,
    const int* __restrict__ idx_h, const int* __restrict__ idx_w,
    unsigned short* __restrict__ kfb, unsigned short* __restrict__ vtb){
  int Bp = blockIdx.x; int b = Bp>>3, hd = Bp&7;
  __shared__ int hi[16], wj[16];
  __shared__ int pos_s[256];
  if (threadIdx.x < 16) hi[threadIdx.x] = idx_h[Bp*16+threadIdx.x];
  else if (threadIdx.x < 32) wj[threadIdx.x-16] = idx_w[Bp*16+threadIdx.x-16];
  __syncthreads();
  pos_s[threadIdx.x] = hi[threadIdx.x>>4]*64 + wj[threadIdx.x&15];
  __syncthreads();
  const float* kpl = qkv + ((size_t)b*768 + 256 + hd*32)*(size_t)HW;
  const float* vpl = qkv + ((size_t)b*768 + 512 + hd*32)*(size_t)HW;
  for (int e=threadIdx.x; e<8192; e+=256){
    int t = e>>5, c = e&31;
    kfb[(size_t)Bp*8192 + e] = bf16r(kpl[(size_t)c*HW + pos_s[t]]);
    int c2 = e>>8, t2 = e&255;
    vtb[(size_t)Bp*8192 + e] = bf16r(vpl[(size_t)c2*HW + pos_s[t2]]);
  }
}

// ---------------------------------------------------------------------------
// MFMA attention: per block (Bp, 64-query tile); no max-tracking softmax.
// K,V read from global (L2-resident); P through padded LDS. All intra-wave.
__global__ __launch_bounds__(256) void k_attn_mfma(
    const unsigned short* __restrict__ QT,
    const unsigned short* __restrict__ kfb,
    const unsigned short* __restrict__ vtb,
    unsigned short* __restrict__ xout){
  __shared__ unsigned short Pl[4*16*264];
  __shared__ unsigned short obuf[4*16*32];
  __shared__ float lsum[64];
  int Bp = blockIdx.y, qb = blockIdx.x*64;
  int b = Bp>>3, hd = Bp&7;
  int tid = threadIdx.x;
  int wv = tid>>6, lane = tid&63, l15 = lane&15, lq = lane>>4;

  const unsigned short* Kg = kfb + (size_t)Bp*8192;
  const unsigned short* Vg = vtb + (size_t)Bp*8192;

  // Q A-fragment (coalesced 16B/lane)
  bfrag aq = *(const bfrag*)(QT + ((size_t)Bp*4096 + qb + wv*16 + l15)*32 + lq*8);

  // QK^T + exp + P->LDS + rowsum
  float ps[4] = {0.f,0.f,0.f,0.f};
  #pragma unroll
  for (int t=0;t<16;t++){
    bfrag bk = *(const bfrag*)(Kg + (t*16+l15)*32 + lq*8);
    facc s = (facc){0.f,0.f,0.f,0.f};
    s = __builtin_amdgcn_mfma_f32_16x16x32_bf16(aq, bk, s, 0,0,0);
    #pragma unroll
    for (int r=0;r<4;r++){
      float pe = __expf(s[r]);
      ps[r] += pe;
      Pl[(wv*16 + lq*4 + r)*264 + t*16 + l15] = bf16r(pe);
    }
  }
  #pragma unroll
  for (int r=0;r<4;r++){
    #pragma unroll
    for (int d=1; d<16; d<<=1) ps[r] += __shfl_xor(ps[r], d, 64);
  }
  if (l15==0){
    #pragma unroll
    for (int r=0;r<4;r++) lsum[wv*16 + lq*4 + r] = ps[r];
  }

  // PV: out[q][vd], contraction over 256 keys (intra-wave LDS, DS in-order)
  facc o0 = (facc){0.f,0.f,0.f,0.f}, o1 = (facc){0.f,0.f,0.f,0.f};
  #pragma unroll
  for (int ko=0;ko<8;ko++){
    bfrag ap = *(const bfrag*)(Pl + (wv*16 + l15)*264 + ko*32 + lq*8);
    bfrag b0 = *(const bfrag*)(Vg + (l15)*256 + ko*32 + lq*8);
    bfrag b1 = *(const bfrag*)(Vg + (16+l15)*256 + ko*32 + lq*8);
    o0 = __builtin_amdgcn_mfma_f32_16x16x32_bf16(ap, b0, o0, 0,0,0);
    o1 = __builtin_amdgcn_mfma_f32_16x16x32_bf16(ap, b1, o1, 0,0,0);
  }
  #pragma unroll
  for (int r=0;r<4;r++){
    float iv = 1.f / lsum[wv*16 + lq*4 + r];
    obuf[(wv*16 + lq*4 + r)*32 + l15]      = bf16r(o0[r]*iv);
    obuf[(wv*16 + lq*4 + r)*32 + 16 + l15] = bf16r(o1[r]*iv);
  }
  // coalesced store (intra-wave: lanes of wave wv read rows [wv*16,wv*16+16))
  int ql = wv*16 + (lane>>2), ch = lane&3;
  us8 hv = *(const us8*)(obuf + ql*32 + ch*8);
  *(us8*)(xout + (size_t)b*6291456ull + (size_t)(qb + ql)*256u + hd*32 + ch*8) = hv;
}

// ---------------------------------------------------------------------------
// fp32 planar -> bf16 transposed [wb][4096][Ktot] at coff
__global__ __launch_bounds__(256) void k_bf16T(const float* __restrict__ in,
    unsigned short* __restrict__ xt, int Cpart, int Ktot, int coff, int rb0, int wb0){
  int rb = rb0 + blockIdx.z, wb = wb0 + blockIdx.z;
  int c0 = blockIdx.y*64, p0 = blockIdx.x*64;
  __shared__ float t[64][65];
  const float* ip = in + ((size_t)rb*Cpart + c0)*(size_t)HW + p0;
  int tr = threadIdx.x>>4, tc4 = (threadIdx.x&15)*4;
  #pragma unroll
  for (int rr=0; rr<64; rr+=16){
    float4 v = *(const float4*)(ip + (size_t)(tr+rr)*HW + tc4);
    t[tr+rr][tc4+0]=v.x; t[tr+rr][tc4+1]=v.y; t[tr+rr][tc4+2]=v.z; t[tr+rr][tc4+3]=v.w;
  }
  __syncthreads();
  unsigned short* xh = xt + (size_t)wb*4096u*(size_t)Ktot + (size_t)coff + c0;
  #pragma unroll
  for (int rr=0; rr<64; rr+=16){
    int p = tr+rr;
    ushort4 hv;
    hv.x = bf16r(t[tc4+0][p]); hv.y = bf16r(t[tc4+1][p]);
    hv.z = bf16r(t[tc4+2][p]); hv.w = bf16r(t[tc4+3][p]);
    *(ushort4*)(xh + (size_t)(p0+p)*(size_t)Ktot + tc4) = hv;
  }
}

// depthwise 3x3 + bf16 transposed write into XT2 cols [256,512)
__global__ __launch_bounds__(256) void k_dwbf16(const float* __restrict__ x,
    const float* __restrict__ w, const float* __restrict__ bias,
    unsigned short* __restrict__ xt){
  int p = blockIdx.x*256 + threadIdx.x;
  int b = p >> 12, pos = p & 4095;
  int h = pos>>6, wx = pos&63;
  int c0 = blockIdx.y*64;
  unsigned short* xh = xt + (size_t)b*2097152ull + (size_t)pos*512u + 256u + c0;
  for (int cc=0; cc<64; cc+=8){
    us8 hv;
    #pragma unroll
    for (int j=0;j<8;j++){
      int c = c0+cc+j;
      const float* ip = x + ((size_t)b*Cd + c)*(size_t)HW;
      const float* wp = w + c*9;
      float s = bias[c];
      #pragma unroll
      for (int kh=-1; kh<=1; ++kh){
        int hh = h+kh; if ((unsigned)hh >= 64u) continue;
        #pragma unroll
        for (int kw=-1; kw<=1; ++kw){
          int ww2 = wx+kw; if ((unsigned)ww2 >= 64u) continue;
          s += wp[(kh+1)*3 + (kw+1)] * ip[hh*64 + ww2];
        }
      }
      hv[j] = bf16r(s);
    }
    *(us8*)(xh+cc) = hv;
  }
}

// ---------------------------------------------------------------------------
__global__ __launch_bounds__(256) void k_ffn_fused(float* __restrict__ h,
    const float* __restrict__ wdw, const float* __restrict__ bdw){
  __shared__ float lds[4096];
  __shared__ float red[8];
  int plane = blockIdx.x;
  int c = plane & 1023;
  float* hp = h + (size_t)plane*(size_t)HW;
  int t = threadIdx.x;
  int wid = t>>6, lane = t&63;

  float4 v[4];
  float s=0.f, ss=0.f;
  #pragma unroll
  for (int k2=0;k2<4;k2++){
    v[k2] = *(const float4*)(hp + k2*1024 + t*4);
    s  += v[k2].x+v[k2].y+v[k2].z+v[k2].w;
    ss += v[k2].x*v[k2].x+v[k2].y*v[k2].y+v[k2].z*v[k2].z+v[k2].w*v[k2].w;
  }
  s = wredsum(s); ss = wredsum(ss);
  if (lane==0){ red[wid]=s; red[4+wid]=ss; }
  __syncthreads();
  s  = red[0]+red[1]+red[2]+red[3];
  ss = red[4]+red[5]+red[6]+red[7];
  float mean = s*(1.f/HW);
  float inv  = rsqrtf(ss*(1.f/HW) - mean*mean + 1e-5f);

  #pragma unroll
  for (int k2=0;k2<4;k2++){
    int i = k2*1024 + t*4;
    lds[i+0] = gelu_exact((v[k2].x-mean)*inv);
    lds[i+1] = gelu_exact((v[k2].y-mean)*inv);
    lds[i+2] = gelu_exact((v[k2].z-mean)*inv);
    lds[i+3] = gelu_exact((v[k2].w-mean)*inv);
  }
  __syncthreads();

  float w9[9];
  #pragma unroll
  for (int i=0;i<9;i++) w9[i] = wdw[c*9+i];
  float bv = bdw[c];
  float r[16];
  float s2=0.f, ss2=0.f;
  #pragma unroll
  for (int k2=0;k2<4;k2++){
    #pragma unroll
    for (int j=0;j<4;j++){
      int px = k2*1024 + t*4 + j;
      int hh = px>>6, ww = px&63;
      float acc = bv;
      #pragma unroll
      for (int kh=-1; kh<=1; ++kh){
        int h2 = hh+kh; if ((unsigned)h2 >= 64u) continue;
        #pragma unroll
        for (int kw=-1; kw<=1; ++kw){
          int w2 = ww+kw; if ((unsigned)w2 >= 64u) continue;
          acc += w9[(kh+1)*3+(kw+1)] * lds[h2*64 + w2];
        }
      }
      r[k2*4+j] = acc;
      s2 += acc; ss2 += acc*acc;
    }
  }
  s2 = wredsum(s2); ss2 = wredsum(ss2);
  __syncthreads();
  if (lane==0){ red[wid]=s2; red[4+wid]=ss2; }
  __syncthreads();
  s2  = red[0]+red[1]+red[2]+red[3];
  ss2 = red[4]+red[5]+red[6]+red[7];
  float mean2 = s2*(1.f/HW);
  float inv2  = rsqrtf(ss2*(1.f/HW) - mean2*mean2 + 1e-5f);

  #pragma unroll
  for (int k2=0;k2<4;k2++){
    int i = k2*1024 + t*4;
    float4 o;
    o.x = lds[i+0] + gelu_exact((r[k2*4+0]-mean2)*inv2);
    o.y = lds[i+1] + gelu_exact((r[k2*4+1]-mean2)*inv2);
    o.z = lds[i+2] + gelu_exact((r[k2*4+2]-mean2)*inv2);
    o.w = lds[i+3] + gelu_exact((r[k2*4+3]-mean2)*inv2);
    *(float4*)(hp + i) = o;
  }
}

// instance norm over HW per plane
__global__ __launch_bounds__(256) void k_instnorm(const float* __restrict__ in,
    float* __restrict__ out){
  size_t base = (size_t)blockIdx.x * HW;
  const float* p = in + base;
  float s=0.f, ss=0.f;
  for (int i=threadIdx.x*4; i<HW; i+=1024){
    float4 v = *(const float4*)(p+i);
    s  += v.x+v.y+v.z+v.w;
    ss += v.x*v.x+v.y*v.y+v.z*v.z+v.w*v.w;
  }
  s = wredsum(s); ss = wredsum(ss);
  __shared__ float sh[8];
  int wid = threadIdx.x>>6;
  if ((threadIdx.x&63)==0){ sh[wid]=s; sh[4+wid]=ss; }
  __syncthreads();
  s  = sh[0]+sh[1]+sh[2]+sh[3];
  ss = sh[4]+sh[5]+sh[6]+sh[7];
  float mean = s*(1.f/HW);
  float inv  = rsqrtf(ss*(1.f/HW) - mean*mean + 1e-5f);
  for (int i=threadIdx.x*4; i<HW; i+=1024){
    float4 v = *(const float4*)(p+i);
    float4 r;
    r.x = (v.x-mean)*inv; r.y = (v.y-mean)*inv; r.z = (v.z-mean)*inv; r.w = (v.w-mean)*inv;
    *(float4*)(out + base + i) = r;
  }
}

// ---------------------------------------------------------------------------
extern "C" void kernel_launch(void* const* d_in, const int* in_sizes, int n_in,
                              void* d_out, int out_size, void* d_ws, size_t ws_size,
                              hipStream_t stream){
  const float* x      = (const float*)d_in[0];
  const float* ln_g   = (const float*)d_in[1];
  const float* ln_bb  = (const float*)d_in[2];
  const float* w_qkv  = (const float*)d_in[3];
  const float* w_out  = (const float*)d_in[4];
  const float* b_out  = (const float*)d_in[5];
  const float* w_dw   = (const float*)d_in[6];
  const float* b_dw   = (const float*)d_in[7];
  const float* w_comb = (const float*)d_in[8];
  const float* b_comb = (const float*)d_in[9];
  const float* w_ff1  = (const float*)d_in[10];
  const float* b_ff1  = (const float*)d_in[11];
  const float* w_ffdw = (const float*)d_in[12];
  const float* b_ffdw = (const float*)d_in[13];
  const float* w_ff2  = (const float*)d_in[14];
  const float* b_ff2  = (const float*)d_in[15];
  float* out = (float*)d_out;
  float* ws  = (float*)d_ws;

  // ---- workspace (float offsets), max 42,860,544 floats = 163.5 MiB ----
  float* A    = ws;                                  // [0, 8.39M) attn_out / XT3a
  float* Q    = ws + 8388608ull;                     // [8.39M, 33.55M) qkv
  float* Hb   = ws + 8388608ull;                     // h (after qkv dead)
  float* F2o  = ws + 8388608ull;                     // ff2 fp32 out (after Hb dead)
  unsigned short* XT2 = (unsigned short*)(ws + 16777216ull);   // comb input bf16
  unsigned short* XTa = (unsigned short*)(ws + 33554432ull);   // qkv input (split)
  unsigned short* QT  = (unsigned short*)(ws + 33554432ull);   // reuse after qkv GEMM
  unsigned short* KFB = (unsigned short*)(ws + 37748736ull);   // K gathered bf16
  unsigned short* VTB = (unsigned short*)(ws + 38010880ull);   // V^T gathered bf16
  unsigned short* Xattn = (unsigned short*)(Q + 2097152ull);   // v-plane reuse
  unsigned short* XT3a = (unsigned short*)ws;                  // A region reuse
  unsigned short* XT3b = (unsigned short*)d_out;               // d_out reuse
  unsigned short* XTb  = (unsigned short*)d_out;               // ff1 input
  float* S = ws;                                     // attention smalls
  float* k_height = S;                     // 131072
  float* k_width  = S + 131072;            // 131072
  float* q_probe  = S + 262144;            // 2048
  float* score_r  = S + 264192;            // 4096
  float* score_c  = S + 268288;            // 4096
  int*   idx_h    = (int*)(S + 272384);    // 1024
  int*   idx_w    = idx_h + 1024;          // 1024
  unsigned short* W2qkv = (unsigned short*)(ws + 41943040ull); // split 393216 us
  unsigned short* Wb_out  = W2qkv + 393216;          // 65536
  unsigned short* Wb_comb = Wb_out + 65536;          // 131072
  unsigned short* Wb_ff1  = Wb_comb + 131072;        // 262144
  unsigned short* Wb_ff2  = Wb_ff1 + 262144;         // 262144

  // weights
  k_splitW<<<(196608+255)/256, 256, 0, stream>>>(w_qkv, W2qkv, 196608);
  k_cvtW<<<(65536 +255)/256, 256, 0, stream>>>(w_out,  Wb_out,  65536);
  k_cvtW<<<(131072+255)/256, 256, 0, stream>>>(w_comb, Wb_comb, 131072);
  k_cvtW<<<(262144+255)/256, 256, 0, stream>>>(w_ff1,  Wb_ff1, 262144);
  k_cvtW<<<(262144+255)/256, 256, 0, stream>>>(w_ff2,  Wb_ff2, 262144);

  // ---- DPSA attention branch ----
  k_lnsplit<<<512, 256, 0, stream>>>(x, ln_g, ln_bb, XTa);
  k_mfma3<<<dim3(32,6,8), 256, 0, stream>>>(W2qkv, XTa, Q, 768, 256, 2097152);
  k_l2norm<<<65536, 256, 0, stream>>>(Q, k_height);
  k_qT<<<dim3(64,64), 256, 0, stream>>>(Q, QT);
  k_qprobe<<<2048, 256, 0, stream>>>(Q, q_probe);
  k_score<<<64, 64, 0, stream>>>(q_probe, k_height, score_r);
  k_topk<<<64, 64, 0, stream>>>(score_r, idx_h);
  k_kwidth<<<dim3(32,64), 64, 0, stream>>>(Q, idx_h, k_width);
  k_score<<<64, 64, 0, stream>>>(q_probe, k_width, score_c);
  k_topk<<<64, 64, 0, stream>>>(score_c, idx_w);
  k_gather_bf<<<64, 256, 0, stream>>>(Q, idx_h, idx_w, KFB, VTB);
  k_attn_mfma<<<dim3(64,64), 256, 0, stream>>>(QT, KFB, VTB, Xattn);
  k_mfma1<false><<<dim3(32,2,8), 256, 0, stream>>>(Wb_out, Xattn, b_out, nullptr, (float*)d_out, 256, 256, 6291456);

  // ---- conv branch + combine + residual ----
  k_bf16T<<<dim3(64,4,8), 256, 0, stream>>>((const float*)d_out, XT2, 256, 512, 0, 0, 0);
  k_dwbf16<<<dim3(128,4), 256, 0, stream>>>(x, w_dw, b_dw, XT2);
  k_mfma1<true><<<dim3(32,2,8), 256, 0, stream>>>(Wb_comb, XT2, b_comb, x, A, 256, 512, 2097152);

  // ---- feedforward ----
  k_bf16T<<<dim3(64,4,8), 256, 0, stream>>>(A, XTb, 256, 256, 0, 0, 0);
  k_mfma1<false><<<dim3(32,8,8), 256, 0, stream>>>(Wb_ff1, XTb, b_ff1, nullptr, Hb, 1024, 256, 1048576);
  k_ffn_fused<<<Bn*1024, 256, 0, stream>>>(Hb, w_ffdw, b_ffdw);
  // h -> bf16 transposed: batches 0-3 into dead A region, 4-7 into dead d_out
  k_bf16T<<<dim3(64,16,4), 256, 0, stream>>>(Hb, XT3a, 1024, 1024, 0, 0, 0);
  k_bf16T<<<dim3(64,16,4), 256, 0, stream>>>(Hb, XT3b, 1024, 1024, 0, 4, 0);
  k_mfma1<false><<<dim3(32,2,4), 256, 0, stream>>>(Wb_ff2, XT3a, b_ff2, nullptr, F2o, 256, 1024, 4194304);
  k_mfma1<false><<<dim3(32,2,4), 256, 0, stream>>>(Wb_ff2, XT3b, b_ff2, nullptr, F2o + 4ull*256*HW, 256, 1024, 4194304);
  k_instnorm<<<Bn*256, 256, 0, stream>>>(F2o, (float*)d_out);
}

// Round 11
// 813.115 us; speedup vs baseline: 1.7266x; 1.0636x over previous
//
#include <hip/hip_runtime.h>
#include <math.h>

// Problem dims
constexpr int Bn = 8, Cd = 256, HW = 4096;
constexpr int NPOS = Bn * HW;

typedef __attribute__((ext_vector_type(8))) short bfrag;            // 8 bf16
typedef __attribute__((ext_vector_type(4))) float facc;             // 4 fp32
typedef __attribute__((ext_vector_type(8))) unsigned short us8;     // 16B

static __device__ __forceinline__ float wredsum(float v){
  #pragma unroll
  for (int d=32; d; d>>=1) v += __shfl_xor(v,d,64);
  return v;
}
static __device__ __forceinline__ float gelu_exact(float x){
  return 0.5f*x*(1.f+erff(x*0.70710678118f));
}
static __device__ __forceinline__ unsigned short bf16r(float x){
  unsigned u = __float_as_uint(x);
  u += 0x7FFFu + ((u>>16)&1u);
  return (unsigned short)(u>>16);
}
// split fp32 -> bf16 hi + bf16 lo
static __device__ __forceinline__ void split1(float x, unsigned short& h, unsigned short& l){
  unsigned u = __float_as_uint(x);
  unsigned r = (u + 0x7FFFu + ((u>>16)&1u)) & 0xFFFF0000u;
  h = (unsigned short)(r>>16);
  float rest = x - __uint_as_float(r);
  unsigned u2 = __float_as_uint(rest);
  unsigned r2 = u2 + 0x7FFFu + ((u2>>16)&1u);
  l = (unsigned short)(r2>>16);
}

// ---------------------------------------------------------------------------
// FUSED channel-LN + split + transpose, LDS-staged coalesced writes.
// Block: 64 px x 4 c-groups. Writes hi/lo planes as contiguous us8 runs.
__global__ __launch_bounds__(256) void k_lnsplit(const float* __restrict__ x,
    const float* __restrict__ g, const float* __restrict__ bb,
    unsigned short* __restrict__ xt){
  __shared__ float rs[64][5], rss[64][5];
  __shared__ unsigned short lt[64*262];     // [64 px][256 ch], stride 262 (bank-spread)
  int tid = threadIdx.x;
  int pxi = tid & 63;
  int cg  = tid >> 6;
  int p = blockIdx.x*64 + pxi;
  int b = p >> 12, pos = p & 4095;
  int pos0 = (blockIdx.x*64) & 4095;
  const float* xb = x + ((size_t)b*Cd + cg*64)*(size_t)HW + pos;
  float s=0.f, ss=0.f;
  #pragma unroll 8
  for (int c=0;c<64;c++){ float v = xb[(size_t)c*HW]; s+=v; ss+=v*v; }
  rs[pxi][cg]=s; rss[pxi][cg]=ss;
  __syncthreads();
  s  = rs[pxi][0]+rs[pxi][1]+rs[pxi][2]+rs[pxi][3];
  ss = rss[pxi][0]+rss[pxi][1]+rss[pxi][2]+rss[pxi][3];
  float mean = s*(1.f/Cd);
  float inv  = rsqrtf(ss*(1.f/Cd) - mean*mean + 1e-5f);

  // phase2a: hi -> LDS, lo -> regs
  us8 lv_r[8];
  #pragma unroll
  for (int c0=0;c0<64;c0+=8){
    #pragma unroll
    for (int j=0;j<8;j++){
      float v = xb[(size_t)(c0+j)*HW];
      v = (v-mean)*inv*g[cg*64+c0+j] + bb[cg*64+c0+j];
      unsigned short hh,ll; split1(v,hh,ll);
      lt[pxi*262 + cg*64 + c0 + j] = hh;
      lv_r[c0>>3][j] = ll;
    }
  }
  __syncthreads();
  unsigned short* xp = xt + (size_t)b*2097152ull + (size_t)pos0*256u;
  #pragma unroll
  for (int i=0;i<8;i++){
    int e = i*256 + tid;
    int pl = e>>5, ch = e&31;
    us8 hv;
    #pragma unroll
    for (int j=0;j<8;j++) hv[j] = lt[pl*262 + ch*8 + j];
    *(us8*)(xp + (size_t)pl*256u + ch*8) = hv;
  }
  __syncthreads();
  #pragma unroll
  for (int c0=0;c0<64;c0+=8)
    #pragma unroll
    for (int j=0;j<8;j++) lt[pxi*262 + cg*64 + c0 + j] = lv_r[c0>>3][j];
  __syncthreads();
  #pragma unroll
  for (int i=0;i<8;i++){
    int e = i*256 + tid;
    int pl = e>>5, ch = e&31;
    us8 hv;
    #pragma unroll
    for (int j=0;j<8;j++) hv[j] = lt[pl*262 + ch*8 + j];
    *(us8*)(xp + 1048576u + (size_t)pl*256u + ch*8) = hv;
  }
}

// weight split (qkv only)
__global__ void k_splitW(const float* __restrict__ w, unsigned short* __restrict__ wh, int n){
  int i = blockIdx.x*256 + threadIdx.x;
  if (i<n){
    unsigned short h,l; split1(w[i],h,l);
    wh[i]=h; wh[n+i]=l;
  }
}
// plain weight convert
__global__ void k_cvtW(const float* __restrict__ w, unsigned short* __restrict__ wb, int n){
  int i = blockIdx.x*256 + threadIdx.x;
  if (i<n) wb[i] = bf16r(w[i]);
}

// ---------------------------------------------------------------------------
// 3-term split MFMA GEMM (qkv only)
__global__ __launch_bounds__(256) void k_mfma3(
    const unsigned short* __restrict__ W2,
    const unsigned short* __restrict__ Xt,
    float* __restrict__ out, int M, int K, long xbs){
  int b  = blockIdx.z;
  int n0 = blockIdx.x*128;
  int m0 = blockIdx.y*128;
  int wave = threadIdx.x>>6, lane = threadIdx.x&63;
  int wm = (wave>>1)*64, wn = (wave&1)*64;
  int l15 = lane&15, half = lane>>4;
  const unsigned short* Wh = W2;
  const unsigned short* Wl = W2 + (size_t)M*K;
  const unsigned short* Xh = Xt + (size_t)b*(size_t)xbs;
  const unsigned short* Xl = Xh + (size_t)4096u*(size_t)K;

  facc acc[4][4];
  #pragma unroll
  for (int i=0;i<4;i++)
    #pragma unroll
    for (int j=0;j<4;j++) acc[i][j] = (facc){0.f,0.f,0.f,0.f};

  const size_t wrow[4] = {
    (size_t)(m0+wm+ 0+l15)*(size_t)K, (size_t)(m0+wm+16+l15)*(size_t)K,
    (size_t)(m0+wm+32+l15)*(size_t)K, (size_t)(m0+wm+48+l15)*(size_t)K };
  const size_t xrow[4] = {
    (size_t)(n0+wn+ 0+l15)*(size_t)K, (size_t)(n0+wn+16+l15)*(size_t)K,
    (size_t)(n0+wn+32+l15)*(size_t)K, (size_t)(n0+wn+48+l15)*(size_t)K };

  for (int k0=0; k0<K; k0+=32){
    int ks = k0 + half*8;
    bfrag ah[4], al[4], bh[4], bl[4];
    #pragma unroll
    for (int i=0;i<4;i++){
      ah[i] = *(const bfrag*)(Wh + wrow[i] + ks);
      al[i] = *(const bfrag*)(Wl + wrow[i] + ks);
      bh[i] = *(const bfrag*)(Xh + xrow[i] + ks);
      bl[i] = *(const bfrag*)(Xl + xrow[i] + ks);
    }
    #pragma unroll
    for (int i=0;i<4;i++)
      #pragma unroll
      for (int j=0;j<4;j++){
        acc[i][j] = __builtin_amdgcn_mfma_f32_16x16x32_bf16(ah[i], bh[j], acc[i][j],0,0,0);
        acc[i][j] = __builtin_amdgcn_mfma_f32_16x16x32_bf16(ah[i], bl[j], acc[i][j],0,0,0);
        acc[i][j] = __builtin_amdgcn_mfma_f32_16x16x32_bf16(al[i], bh[j], acc[i][j],0,0,0);
      }
  }
  #pragma unroll
  for (int i=0;i<4;i++){
    int o = m0+wm+i*16+half*4;
    #pragma unroll
    for (int j=0;j<4;j++){
      int p = n0+wn+j*16+l15;
      size_t ob = ((size_t)b*M + o)*(size_t)HW + p;
      #pragma unroll
      for (int r=0;r<4;r++)
        out[ob + (size_t)r*HW] = acc[i][j][r];
    }
  }
}

// ---------------------------------------------------------------------------
// plain bf16 MFMA GEMM
template<bool RES>
__global__ __launch_bounds__(256) void k_mfma1(
    const unsigned short* __restrict__ Wb,
    const unsigned short* __restrict__ Xt,
    const float* __restrict__ bias, const float* __restrict__ resid,
    float* __restrict__ out, int M, int K, long xbs){
  int b  = blockIdx.z;
  int n0 = blockIdx.x*128;
  int m0 = blockIdx.y*128;
  int wave = threadIdx.x>>6, lane = threadIdx.x&63;
  int wm = (wave>>1)*64, wn = (wave&1)*64;
  int l15 = lane&15, half = lane>>4;
  const unsigned short* Xh = Xt + (size_t)b*(size_t)xbs;

  facc acc[4][4];
  #pragma unroll
  for (int i=0;i<4;i++)
    #pragma unroll
    for (int j=0;j<4;j++) acc[i][j] = (facc){0.f,0.f,0.f,0.f};

  const size_t wrow[4] = {
    (size_t)(m0+wm+ 0+l15)*(size_t)K, (size_t)(m0+wm+16+l15)*(size_t)K,
    (size_t)(m0+wm+32+l15)*(size_t)K, (size_t)(m0+wm+48+l15)*(size_t)K };
  const size_t xrow[4] = {
    (size_t)(n0+wn+ 0+l15)*(size_t)K, (size_t)(n0+wn+16+l15)*(size_t)K,
    (size_t)(n0+wn+32+l15)*(size_t)K, (size_t)(n0+wn+48+l15)*(size_t)K };

  #pragma unroll 2
  for (int k0=0; k0<K; k0+=32){
    int ks = k0 + half*8;
    bfrag ah[4], bh[4];
    #pragma unroll
    for (int i=0;i<4;i++){
      ah[i] = *(const bfrag*)(Wb + wrow[i] + ks);
      bh[i] = *(const bfrag*)(Xh + xrow[i] + ks);
    }
    #pragma unroll
    for (int i=0;i<4;i++)
      #pragma unroll
      for (int j=0;j<4;j++)
        acc[i][j] = __builtin_amdgcn_mfma_f32_16x16x32_bf16(ah[i], bh[j], acc[i][j],0,0,0);
  }
  #pragma unroll
  for (int i=0;i<4;i++){
    int o = m0+wm+i*16+half*4;
    #pragma unroll
    for (int j=0;j<4;j++){
      int p = n0+wn+j*16+l15;
      size_t ob = ((size_t)b*M + o)*(size_t)HW + p;
      #pragma unroll
      for (int r=0;r<4;r++){
        float v = acc[i][j][r];
        if (bias) v += bias[o+r];
        if (RES)  v += resid[ob + (size_t)r*HW];
        out[ob + (size_t)r*HW] = v;
      }
    }
  }
}

// ---------------------------------------------------------------------------
// l2norm along W (vectorized float4, 16 lanes/row); in-place on q,k.
// Emits per-row sums: k rows -> k_height, q rows -> qrow.
__global__ __launch_bounds__(256) void k_l2norm(float* __restrict__ qkv,
    float* __restrict__ k_height, float* __restrict__ qrow){
  int row = blockIdx.x*16 + (threadIdx.x>>4);
  int l16 = threadIdx.x & 15;
  int part = row >> 17;
  int rem  = row & 131071;
  int Bp   = rem >> 11;
  int c    = (rem >> 6) & 31;
  int h    = rem & 63;
  int b = Bp>>3, hd = Bp&7;
  float* ptr = qkv + ((size_t)b*768 + part*256 + hd*32 + c)*(size_t)HW + h*64 + l16*4;
  float4 v = *(const float4*)ptr;
  float ss = v.x*v.x+v.y*v.y+v.z*v.z+v.w*v.w;
  float sv = v.x+v.y+v.z+v.w;
  #pragma unroll
  for (int d=1; d<16; d<<=1){ ss += __shfl_xor(ss,d,64); sv += __shfl_xor(sv,d,64); }
  float inv = 1.f / fmaxf(sqrtf(ss), 1e-12f);
  v.x*=inv; v.y*=inv; v.z*=inv; v.w*=inv;
  *(float4*)ptr = v;
  if (l16==0){
    float rsum = sv*inv;
    if (part) k_height[(size_t)Bp*2048 + c*64 + h] = rsum;
    else      qrow[(size_t)Bp*2048 + c*64 + h] = rsum;
  }
}

// q_probe[Bp][c] = sum_h qrow[Bp][c][h]
__global__ void k_qprobe2(const float* __restrict__ qrow, float* __restrict__ q_probe){
  int Bp = blockIdx.x; int t = threadIdx.x;
  int c = t>>3, h0 = (t&7)*8;
  float s = 0.f;
  #pragma unroll
  for (int j=0;j<8;j++) s += qrow[(size_t)Bp*2048 + c*64 + h0 + j];
  #pragma unroll
  for (int d=1; d<8; d<<=1) s += __shfl_xor(s,d,64);
  if ((t&7)==0) q_probe[Bp*32+c] = s;
}

// Q fp32 planar -> QT [Bp][4096][32] bf16 (post-l2norm)
__global__ __launch_bounds__(256) void k_qT(const float* __restrict__ qkv,
    unsigned short* __restrict__ qt){
  __shared__ float t[64][33];
  int Bp = blockIdx.y, p0 = blockIdx.x*64;
  int b = Bp>>3, hd = Bp&7;
  const float* qp = qkv + ((size_t)b*768 + hd*32)*(size_t)HW + p0;
  int c8 = threadIdx.x>>6, px = threadIdx.x&63;
  #pragma unroll
  for (int j=0;j<8;j++)
    t[px][c8*8+j] = qp[(size_t)(c8*8+j)*HW + px];
  __syncthreads();
  int px2 = threadIdx.x>>2, ch = threadIdx.x&3;
  us8 hv;
  #pragma unroll
  for (int j=0;j<8;j++) hv[j] = bf16r(t[px2][ch*8+j]);
  *(us8*)(qt + ((size_t)Bp*4096 + p0 + px2)*32 + ch*8) = hv;
}

__global__ void k_score(const float* __restrict__ q_probe,
    const float* __restrict__ agg, float* __restrict__ score){
  int Bp = blockIdx.x; int t = threadIdx.x;
  float s = 0.f;
  for (int c=0;c<32;c++) s += q_probe[Bp*32+c] * agg[(size_t)Bp*2048 + c*64 + t];
  score[Bp*64+t] = s;
}

__global__ void k_topk(const float* __restrict__ score, int* __restrict__ idx){
  int Bp = blockIdx.x; int lane = threadIdx.x;
  float v = score[Bp*64+lane];
  for (int it=0; it<16; ++it){
    float m = v;
    #pragma unroll
    for (int d=32; d; d>>=1) m = fmaxf(m, __shfl_xor(m,d,64));
    unsigned long long mask = __ballot(v==m);
    int sel = __ffsll((unsigned long long)mask) - 1;
    if (lane==0) idx[Bp*16+it] = sel;
    if (lane==sel) v = -3.0e38f;
  }
}

__global__ void k_kwidth(const float* __restrict__ qkv, const int* __restrict__ idx_h,
    float* __restrict__ k_width){
  int c = blockIdx.x, Bp = blockIdx.y, w = threadIdx.x;
  int b = Bp>>3, hd = Bp&7;
  const float* kp = qkv + ((size_t)b*768 + 256 + hd*32 + c)*(size_t)HW;
  float s = 0.f;
  for (int i=0;i<16;i++) s += kp[idx_h[Bp*16+i]*64 + w];
  k_width[(size_t)Bp*2048 + c*64 + w] = s;
}

// gather selected K [Bp][256][32] bf16 and V^T [Bp][32][256] bf16
__global__ __launch_bounds__(256) void k_gather_bf(const float* __restrict__ qkv,
    const int* __restrict__ idx_h, const int* __restrict__ idx_w,
    unsigned short* __restrict__ kfb, unsigned short* __restrict__ vtb){
  int Bp = blockIdx.x; int b = Bp>>3, hd = Bp&7;
  __shared__ int hi[16], wj[16];
  __shared__ int pos_s[256];
  if (threadIdx.x < 16) hi[threadIdx.x] = idx_h[Bp*16+threadIdx.x];
  else if (threadIdx.x < 32) wj[threadIdx.x-16] = idx_w[Bp*16+threadIdx.x-16];
  __syncthreads();
  pos_s[threadIdx.x] = hi[threadIdx.x>>4]*64 + wj[threadIdx.x&15];
  __syncthreads();
  const float* kpl = qkv + ((size_t)b*768 + 256 + hd*32)*(size_t)HW;
  const float* vpl = qkv + ((size_t)b*768 + 512 + hd*32)*(size_t)HW;
  for (int e=threadIdx.x; e<8192; e+=256){
    int t = e>>5, c = e&31;
    kfb[(size_t)Bp*8192 + e] = bf16r(kpl[(size_t)c*HW + pos_s[t]]);
    int c2 = e>>8, t2 = e&255;
    vtb[(size_t)Bp*8192 + e] = bf16r(vpl[(size_t)c2*HW + pos_s[t2]]);
  }
}

// ---------------------------------------------------------------------------
// MFMA attention: per block (Bp, 64-query tile); no max-tracking softmax.
__global__ __launch_bounds__(256) void k_attn_mfma(
    const unsigned short* __restrict__ QT,
    const unsigned short* __restrict__ kfb,
    const unsigned short* __restrict__ vtb,
    unsigned short* __restrict__ xout){
  __shared__ unsigned short Pl[4*16*264];
  __shared__ unsigned short obuf[4*16*32];
  __shared__ float lsum[64];
  int Bp = blockIdx.y, qb = blockIdx.x*64;
  int b = Bp>>3, hd = Bp&7;
  int tid = threadIdx.x;
  int wv = tid>>6, lane = tid&63, l15 = lane&15, lq = lane>>4;

  const unsigned short* Kg = kfb + (size_t)Bp*8192;
  const unsigned short* Vg = vtb + (size_t)Bp*8192;

  bfrag aq = *(const bfrag*)(QT + ((size_t)Bp*4096 + qb + wv*16 + l15)*32 + lq*8);

  float ps[4] = {0.f,0.f,0.f,0.f};
  #pragma unroll
  for (int t=0;t<16;t++){
    bfrag bk = *(const bfrag*)(Kg + (t*16+l15)*32 + lq*8);
    facc s = (facc){0.f,0.f,0.f,0.f};
    s = __builtin_amdgcn_mfma_f32_16x16x32_bf16(aq, bk, s, 0,0,0);
    #pragma unroll
    for (int r=0;r<4;r++){
      float pe = __expf(s[r]);
      ps[r] += pe;
      Pl[(wv*16 + lq*4 + r)*264 + t*16 + l15] = bf16r(pe);
    }
  }
  #pragma unroll
  for (int r=0;r<4;r++){
    #pragma unroll
    for (int d=1; d<16; d<<=1) ps[r] += __shfl_xor(ps[r], d, 64);
  }
  if (l15==0){
    #pragma unroll
    for (int r=0;r<4;r++) lsum[wv*16 + lq*4 + r] = ps[r];
  }

  facc o0 = (facc){0.f,0.f,0.f,0.f}, o1 = (facc){0.f,0.f,0.f,0.f};
  #pragma unroll
  for (int ko=0;ko<8;ko++){
    bfrag ap = *(const bfrag*)(Pl + (wv*16 + l15)*264 + ko*32 + lq*8);
    bfrag b0 = *(const bfrag*)(Vg + (l15)*256 + ko*32 + lq*8);
    bfrag b1 = *(const bfrag*)(Vg + (16+l15)*256 + ko*32 + lq*8);
    o0 = __builtin_amdgcn_mfma_f32_16x16x32_bf16(ap, b0, o0, 0,0,0);
    o1 = __builtin_amdgcn_mfma_f32_16x16x32_bf16(ap, b1, o1, 0,0,0);
  }
  #pragma unroll
  for (int r=0;r<4;r++){
    float iv = 1.f / lsum[wv*16 + lq*4 + r];
    obuf[(wv*16 + lq*4 + r)*32 + l15]      = bf16r(o0[r]*iv);
    obuf[(wv*16 + lq*4 + r)*32 + 16 + l15] = bf16r(o1[r]*iv);
  }
  int ql = wv*16 + (lane>>2), ch = lane&3;
  us8 hv = *(const us8*)(obuf + ql*32 + ch*8);
  *(us8*)(xout + (size_t)b*6291456ull + (size_t)(qb + ql)*256u + hd*32 + ch*8) = hv;
}

// ---------------------------------------------------------------------------
// fp32 planar -> bf16 transposed [wb][4096][Ktot] at coff; us8 coalesced writes
__global__ __launch_bounds__(256) void k_bf16T(const float* __restrict__ in,
    unsigned short* __restrict__ xt, int Cpart, int Ktot, int coff, int rb0, int wb0){
  int rb = rb0 + blockIdx.z, wb = wb0 + blockIdx.z;
  int c0 = blockIdx.y*64, p0 = blockIdx.x*64;
  __shared__ float t[64][65];
  const float* ip = in + ((size_t)rb*Cpart + c0)*(size_t)HW + p0;
  int tr = threadIdx.x>>4, tc4 = (threadIdx.x&15)*4;
  #pragma unroll
  for (int rr=0; rr<64; rr+=16){
    float4 v = *(const float4*)(ip + (size_t)(tr+rr)*HW + tc4);
    t[tr+rr][tc4+0]=v.x; t[tr+rr][tc4+1]=v.y; t[tr+rr][tc4+2]=v.z; t[tr+rr][tc4+3]=v.w;
  }
  __syncthreads();
  unsigned short* xh = xt + (size_t)wb*4096u*(size_t)Ktot + (size_t)coff + c0;
  int chunk = threadIdx.x & 7;
  #pragma unroll
  for (int i=0;i<2;i++){
    int pix = (threadIdx.x>>3) + 32*i;
    us8 hv;
    #pragma unroll
    for (int j=0;j<8;j++) hv[j] = bf16r(t[chunk*8+j][pix]);
    *(us8*)(xh + (size_t)(p0+pix)*(size_t)Ktot + chunk*8) = hv;
  }
}

// depthwise 3x3 + bf16 transposed write into XT2 cols [256,512); LDS-staged.
__global__ __launch_bounds__(256) void k_dwbf16(const float* __restrict__ x,
    const float* __restrict__ w, const float* __restrict__ bias,
    unsigned short* __restrict__ xt){
  __shared__ unsigned short lt[256*65];
  int tid = threadIdx.x;
  int p = blockIdx.x*256 + tid;
  int b = p >> 12, pos = p & 4095;
  int pos0 = (blockIdx.x*256) & 4095;
  int h = pos>>6, wx = pos&63;
  int c0 = blockIdx.y*64;
  for (int cc=0; cc<64; cc++){
    int c = c0+cc;
    const float* ip = x + ((size_t)b*Cd + c)*(size_t)HW;
    const float* wp = w + c*9;
    float s = bias[c];
    #pragma unroll
    for (int kh=-1; kh<=1; ++kh){
      int hh = h+kh; if ((unsigned)hh >= 64u) continue;
      #pragma unroll
      for (int kw=-1; kw<=1; ++kw){
        int ww2 = wx+kw; if ((unsigned)ww2 >= 64u) continue;
        s += wp[(kh+1)*3 + (kw+1)] * ip[hh*64 + ww2];
      }
    }
    lt[tid*65 + cc] = bf16r(s);
  }
  __syncthreads();
  int chunk = tid & 7;
  #pragma unroll
  for (int i=0;i<8;i++){
    int row = (tid>>3) + 32*i;
    us8 hv;
    #pragma unroll
    for (int j=0;j<8;j++) hv[j] = lt[row*65 + chunk*8 + j];
    *(us8*)(xt + (size_t)b*2097152ull + (size_t)(pos0+row)*512u + 256u + c0 + chunk*8) = hv;
  }
}

// ---------------------------------------------------------------------------
__global__ __launch_bounds__(256) void k_ffn_fused(float* __restrict__ h,
    const float* __restrict__ wdw, const float* __restrict__ bdw){
  __shared__ float lds[4096];
  __shared__ float red[8];
  int plane = blockIdx.x;
  int c = plane & 1023;
  float* hp = h + (size_t)plane*(size_t)HW;
  int t = threadIdx.x;
  int wid = t>>6, lane = t&63;

  float4 v[4];
  float s=0.f, ss=0.f;
  #pragma unroll
  for (int k2=0;k2<4;k2++){
    v[k2] = *(const float4*)(hp + k2*1024 + t*4);
    s  += v[k2].x+v[k2].y+v[k2].z+v[k2].w;
    ss += v[k2].x*v[k2].x+v[k2].y*v[k2].y+v[k2].z*v[k2].z+v[k2].w*v[k2].w;
  }
  s = wredsum(s); ss = wredsum(ss);
  if (lane==0){ red[wid]=s; red[4+wid]=ss; }
  __syncthreads();
  s  = red[0]+red[1]+red[2]+red[3];
  ss = red[4]+red[5]+red[6]+red[7];
  float mean = s*(1.f/HW);
  float inv  = rsqrtf(ss*(1.f/HW) - mean*mean + 1e-5f);

  #pragma unroll
  for (int k2=0;k2<4;k2++){
    int i = k2*1024 + t*4;
    lds[i+0] = gelu_exact((v[k2].x-mean)*inv);
    lds[i+1] = gelu_exact((v[k2].y-mean)*inv);
    lds[i+2] = gelu_exact((v[k2].z-mean)*inv);
    lds[i+3] = gelu_exact((v[k2].w-mean)*inv);
  }
  __syncthreads();

  float w9[9];
  #pragma unroll
  for (int i=0;i<9;i++) w9[i] = wdw[c*9+i];
  float bv = bdw[c];
  float r[16];
  float s2=0.f, ss2=0.f;
  #pragma unroll
  for (int k2=0;k2<4;k2++){
    #pragma unroll
    for (int j=0;j<4;j++){
      int px = k2*1024 + t*4 + j;
      int hh = px>>6, ww = px&63;
      float acc = bv;
      #pragma unroll
      for (int kh=-1; kh<=1; ++kh){
        int h2 = hh+kh; if ((unsigned)h2 >= 64u) continue;
        #pragma unroll
        for (int kw=-1; kw<=1; ++kw){
          int w2 = ww+kw; if ((unsigned)w2 >= 64u) continue;
          acc += w9[(kh+1)*3+(kw+1)] * lds[h2*64 + w2];
        }
      }
      r[k2*4+j] = acc;
      s2 += acc; ss2 += acc*acc;
    }
  }
  s2 = wredsum(s2); ss2 = wredsum(ss2);
  __syncthreads();
  if (lane==0){ red[wid]=s2; red[4+wid]=ss2; }
  __syncthreads();
  s2  = red[0]+red[1]+red[2]+red[3];
  ss2 = red[4]+red[5]+red[6]+red[7];
  float mean2 = s2*(1.f/HW);
  float inv2  = rsqrtf(ss2*(1.f/HW) - mean2*mean2 + 1e-5f);

  #pragma unroll
  for (int k2=0;k2<4;k2++){
    int i = k2*1024 + t*4;
    float4 o;
    o.x = lds[i+0] + gelu_exact((r[k2*4+0]-mean2)*inv2);
    o.y = lds[i+1] + gelu_exact((r[k2*4+1]-mean2)*inv2);
    o.z = lds[i+2] + gelu_exact((r[k2*4+2]-mean2)*inv2);
    o.w = lds[i+3] + gelu_exact((r[k2*4+3]-mean2)*inv2);
    *(float4*)(hp + i) = o;
  }
}

// instance norm over HW per plane
__global__ __launch_bounds__(256) void k_instnorm(const float* __restrict__ in,
    float* __restrict__ out){
  size_t base = (size_t)blockIdx.x * HW;
  const float* p = in + base;
  float s=0.f, ss=0.f;
  for (int i=threadIdx.x*4; i<HW; i+=1024){
    float4 v = *(const float4*)(p+i);
    s  += v.x+v.y+v.z+v.w;
    ss += v.x*v.x+v.y*v.y+v.z*v.z+v.w*v.w;
  }
  s = wredsum(s); ss = wredsum(ss);
  __shared__ float sh[8];
  int wid = threadIdx.x>>6;
  if ((threadIdx.x&63)==0){ sh[wid]=s; sh[4+wid]=ss; }
  __syncthreads();
  s  = sh[0]+sh[1]+sh[2]+sh[3];
  ss = sh[4]+sh[5]+sh[6]+sh[7];
  float mean = s*(1.f/HW);
  float inv  = rsqrtf(ss*(1.f/HW) - mean*mean + 1e-5f);
  for (int i=threadIdx.x*4; i<HW; i+=1024){
    float4 v = *(const float4*)(p+i);
    float4 r;
    r.x = (v.x-mean)*inv; r.y = (v.y-mean)*inv; r.z = (v.z-mean)*inv; r.w = (v.w-mean)*inv;
    *(float4*)(out + base + i) = r;
  }
}

// ---------------------------------------------------------------------------
extern "C" void kernel_launch(void* const* d_in, const int* in_sizes, int n_in,
                              void* d_out, int out_size, void* d_ws, size_t ws_size,
                              hipStream_t stream){
  const float* x      = (const float*)d_in[0];
  const float* ln_g   = (const float*)d_in[1];
  const float* ln_bb  = (const float*)d_in[2];
  const float* w_qkv  = (const float*)d_in[3];
  const float* w_out  = (const float*)d_in[4];
  const float* b_out  = (const float*)d_in[5];
  const float* w_dw   = (const float*)d_in[6];
  const float* b_dw   = (const float*)d_in[7];
  const float* w_comb = (const float*)d_in[8];
  const float* b_comb = (const float*)d_in[9];
  const float* w_ff1  = (const float*)d_in[10];
  const float* b_ff1  = (const float*)d_in[11];
  const float* w_ffdw = (const float*)d_in[12];
  const float* b_ffdw = (const float*)d_in[13];
  const float* w_ff2  = (const float*)d_in[14];
  const float* b_ff2  = (const float*)d_in[15];
  float* out = (float*)d_out;
  float* ws  = (float*)d_ws;

  // ---- workspace (float offsets), ~163.5 MiB ----
  float* A    = ws;                                  // [0, 8.39M) attn_out / XT3a
  float* Q    = ws + 8388608ull;                     // [8.39M, 33.55M) qkv
  float* Hb   = ws + 8388608ull;                     // h (after qkv dead)
  float* F2o  = ws + 8388608ull;                     // ff2 fp32 out (after Hb dead)
  unsigned short* XT2 = (unsigned short*)(ws + 16777216ull);   // comb input bf16
  unsigned short* XTa = (unsigned short*)(ws + 33554432ull);   // qkv input (split)
  unsigned short* QT  = (unsigned short*)(ws + 33554432ull);   // reuse after qkv GEMM
  unsigned short* KFB = (unsigned short*)(ws + 37748736ull);   // K gathered bf16
  unsigned short* VTB = (unsigned short*)(ws + 38010880ull);   // V^T gathered bf16
  unsigned short* Xattn = (unsigned short*)(Q + 2097152ull);   // v-plane reuse
  unsigned short* XT3a = (unsigned short*)ws;                  // A region reuse
  unsigned short* XT3b = (unsigned short*)d_out;               // d_out reuse
  unsigned short* XTb  = (unsigned short*)d_out;               // ff1 input
  float* S = ws;                                     // attention smalls (in A region)
  float* k_height = S;                      // 131072
  float* k_width  = S + 131072;             // 131072
  float* qrow     = S + 262144;             // 131072
  float* q_probe  = S + 393216;             // 2048
  float* score_r  = S + 395264;             // 4096
  float* score_c  = S + 399360;             // 4096
  int*   idx_h    = (int*)(S + 403456);     // 1024
  int*   idx_w    = idx_h + 1024;           // 1024
  unsigned short* W2qkv = (unsigned short*)(ws + 41943040ull); // split 393216 us
  unsigned short* Wb_out  = W2qkv + 393216;          // 65536
  unsigned short* Wb_comb = Wb_out + 65536;          // 131072
  unsigned short* Wb_ff1  = Wb_comb + 131072;        // 262144
  unsigned short* Wb_ff2  = Wb_ff1 + 262144;         // 262144

  // weights
  k_splitW<<<(196608+255)/256, 256, 0, stream>>>(w_qkv, W2qkv, 196608);
  k_cvtW<<<(65536 +255)/256, 256, 0, stream>>>(w_out,  Wb_out,  65536);
  k_cvtW<<<(131072+255)/256, 256, 0, stream>>>(w_comb, Wb_comb, 131072);
  k_cvtW<<<(262144+255)/256, 256, 0, stream>>>(w_ff1,  Wb_ff1, 262144);
  k_cvtW<<<(262144+255)/256, 256, 0, stream>>>(w_ff2,  Wb_ff2, 262144);

  // ---- DPSA attention branch ----
  k_lnsplit<<<512, 256, 0, stream>>>(x, ln_g, ln_bb, XTa);
  k_mfma3<<<dim3(32,6,8), 256, 0, stream>>>(W2qkv, XTa, Q, 768, 256, 2097152);
  k_l2norm<<<16384, 256, 0, stream>>>(Q, k_height, qrow);
  k_qprobe2<<<64, 256, 0, stream>>>(qrow, q_probe);
  k_qT<<<dim3(64,64), 256, 0, stream>>>(Q, QT);
  k_score<<<64, 64, 0, stream>>>(q_probe, k_height, score_r);
  k_topk<<<64, 64, 0, stream>>>(score_r, idx_h);
  k_kwidth<<<dim3(32,64), 64, 0, stream>>>(Q, idx_h, k_width);
  k_score<<<64, 64, 0, stream>>>(q_probe, k_width, score_c);
  k_topk<<<64, 64, 0, stream>>>(score_c, idx_w);
  k_gather_bf<<<64, 256, 0, stream>>>(Q, idx_h, idx_w, KFB, VTB);
  k_attn_mfma<<<dim3(64,64), 256, 0, stream>>>(QT, KFB, VTB, Xattn);
  k_mfma1<false><<<dim3(32,2,8), 256, 0, stream>>>(Wb_out, Xattn, b_out, nullptr, (float*)d_out, 256, 256, 6291456);

  // ---- conv branch + combine + residual ----
  k_bf16T<<<dim3(64,4,8), 256, 0, stream>>>((const float*)d_out, XT2, 256, 512, 0, 0, 0);
  k_dwbf16<<<dim3(128,4), 256, 0, stream>>>(x, w_dw, b_dw, XT2);
  k_mfma1<true><<<dim3(32,2,8), 256, 0, stream>>>(Wb_comb, XT2, b_comb, x, A, 256, 512, 2097152);

  // ---- feedforward ----
  k_bf16T<<<dim3(64,4,8), 256, 0, stream>>>(A, XTb, 256, 256, 0, 0, 0);
  k_mfma1<false><<<dim3(32,8,8), 256, 0, stream>>>(Wb_ff1, XTb, b_ff1, nullptr, Hb, 1024, 256, 1048576);
  k_ffn_fused<<<Bn*1024, 256, 0, stream>>>(Hb, w_ffdw, b_ffdw);
  // h -> bf16 transposed: batches 0-3 into dead A region, 4-7 into dead d_out
  k_bf16T<<<dim3(64,16,4), 256, 0, stream>>>(Hb, XT3a, 1024, 1024, 0, 0, 0);
  k_bf16T<<<dim3(64,16,4), 256, 0, stream>>>(Hb, XT3b, 1024, 1024, 0, 4, 0);
  k_mfma1<false><<<dim3(32,2,4), 256, 0, stream>>>(Wb_ff2, XT3a, b_ff2, nullptr, F2o, 256, 1024, 4194304);
  k_mfma1<false><<<dim3(32,2,4), 256, 0, stream>>>(Wb_ff2, XT3b, b_ff2, nullptr, F2o + 4ull*256*HW, 256, 1024, 4194304);
  k_instnorm<<<Bn*256, 256, 0, stream>>>(F2o, (float*)d_out);
}

// Round 12
// 793.463 us; speedup vs baseline: 1.7694x; 1.0248x over previous
//
#include <hip/hip_runtime.h>
#include <math.h>

// Problem dims
constexpr int Bn = 8, Cd = 256, HW = 4096;
constexpr int NPOS = Bn * HW;

typedef __attribute__((ext_vector_type(8))) short bfrag;            // 8 bf16
typedef __attribute__((ext_vector_type(4))) float facc;             // 4 fp32
typedef __attribute__((ext_vector_type(8))) unsigned short us8;     // 16B

static __device__ __forceinline__ float wredsum(float v){
  #pragma unroll
  for (int d=32; d; d>>=1) v += __shfl_xor(v,d,64);
  return v;
}
static __device__ __forceinline__ float gelu_exact(float x){
  return 0.5f*x*(1.f+erff(x*0.70710678118f));
}
// exact-gelu via A&S 7.1.26 erf approx (|err|<2.5e-7): 5-FMA Horner + v_exp
static __device__ __forceinline__ float gelu_fast(float x){
  float ax = fabsf(x)*0.70710678118f;
  float t  = __builtin_amdgcn_rcpf(1.f + 0.3275911f*ax);
  float poly = t*(0.254829592f + t*(-0.284496736f + t*(1.421413741f +
               t*(-1.453152027f + t*1.061405429f))));
  float erfv = 1.f - poly*__expf(-ax*ax);
  erfv = copysignf(erfv, x);
  return 0.5f*x*(1.f+erfv);
}
static __device__ __forceinline__ unsigned short bf16r(float x){
  unsigned u = __float_as_uint(x);
  u += 0x7FFFu + ((u>>16)&1u);
  return (unsigned short)(u>>16);
}
// split fp32 -> bf16 hi + bf16 lo
static __device__ __forceinline__ void split1(float x, unsigned short& h, unsigned short& l){
  unsigned u = __float_as_uint(x);
  unsigned r = (u + 0x7FFFu + ((u>>16)&1u)) & 0xFFFF0000u;
  h = (unsigned short)(r>>16);
  float rest = x - __uint_as_float(r);
  unsigned u2 = __float_as_uint(rest);
  unsigned r2 = u2 + 0x7FFFu + ((u2>>16)&1u);
  l = (unsigned short)(r2>>16);
}

// ---------------------------------------------------------------------------
// FUSED channel-LN + split + transpose, LDS-staged coalesced writes.
// Block: 64 px x 4 c-groups. Writes hi/lo planes as contiguous us8 runs.
__global__ __launch_bounds__(256) void k_lnsplit(const float* __restrict__ x,
    const float* __restrict__ g, const float* __restrict__ bb,
    unsigned short* __restrict__ xt){
  __shared__ float rs[64][5], rss[64][5];
  __shared__ unsigned short lt[64*262];     // [64 px][256 ch], stride 262 (bank-spread)
  int tid = threadIdx.x;
  int pxi = tid & 63;
  int cg  = tid >> 6;
  int p = blockIdx.x*64 + pxi;
  int b = p >> 12, pos = p & 4095;
  int pos0 = (blockIdx.x*64) & 4095;
  const float* xb = x + ((size_t)b*Cd + cg*64)*(size_t)HW + pos;
  float s=0.f, ss=0.f;
  #pragma unroll 8
  for (int c=0;c<64;c++){ float v = xb[(size_t)c*HW]; s+=v; ss+=v*v; }
  rs[pxi][cg]=s; rss[pxi][cg]=ss;
  __syncthreads();
  s  = rs[pxi][0]+rs[pxi][1]+rs[pxi][2]+rs[pxi][3];
  ss = rss[pxi][0]+rss[pxi][1]+rss[pxi][2]+rss[pxi][3];
  float mean = s*(1.f/Cd);
  float inv  = rsqrtf(ss*(1.f/Cd) - mean*mean + 1e-5f);

  // phase2a: hi -> LDS, lo -> regs
  us8 lv_r[8];
  #pragma unroll
  for (int c0=0;c0<64;c0+=8){
    #pragma unroll
    for (int j=0;j<8;j++){
      float v = xb[(size_t)(c0+j)*HW];
      v = (v-mean)*inv*g[cg*64+c0+j] + bb[cg*64+c0+j];
      unsigned short hh,ll; split1(v,hh,ll);
      lt[pxi*262 + cg*64 + c0 + j] = hh;
      lv_r[c0>>3][j] = ll;
    }
  }
  __syncthreads();
  unsigned short* xp = xt + (size_t)b*2097152ull + (size_t)pos0*256u;
  #pragma unroll
  for (int i=0;i<8;i++){
    int e = i*256 + tid;
    int pl = e>>5, ch = e&31;
    us8 hv;
    #pragma unroll
    for (int j=0;j<8;j++) hv[j] = lt[pl*262 + ch*8 + j];
    *(us8*)(xp + (size_t)pl*256u + ch*8) = hv;
  }
  __syncthreads();
  #pragma unroll
  for (int c0=0;c0<64;c0+=8)
    #pragma unroll
    for (int j=0;j<8;j++) lt[pxi*262 + cg*64 + c0 + j] = lv_r[c0>>3][j];
  __syncthreads();
  #pragma unroll
  for (int i=0;i<8;i++){
    int e = i*256 + tid;
    int pl = e>>5, ch = e&31;
    us8 hv;
    #pragma unroll
    for (int j=0;j<8;j++) hv[j] = lt[pl*262 + ch*8 + j];
    *(us8*)(xp + 1048576u + (size_t)pl*256u + ch*8) = hv;
  }
}

// weight split (qkv only)
__global__ void k_splitW(const float* __restrict__ w, unsigned short* __restrict__ wh, int n){
  int i = blockIdx.x*256 + threadIdx.x;
  if (i<n){
    unsigned short h,l; split1(w[i],h,l);
    wh[i]=h; wh[n+i]=l;
  }
}
// plain weight convert
__global__ void k_cvtW(const float* __restrict__ w, unsigned short* __restrict__ wb, int n){
  int i = blockIdx.x*256 + threadIdx.x;
  if (i<n) wb[i] = bf16r(w[i]);
}

// ---------------------------------------------------------------------------
// 3-term split MFMA GEMM (qkv only)
__global__ __launch_bounds__(256) void k_mfma3(
    const unsigned short* __restrict__ W2,
    const unsigned short* __restrict__ Xt,
    float* __restrict__ out, int M, int K, long xbs){
  int b  = blockIdx.z;
  int n0 = blockIdx.x*128;
  int m0 = blockIdx.y*128;
  int wave = threadIdx.x>>6, lane = threadIdx.x&63;
  int wm = (wave>>1)*64, wn = (wave&1)*64;
  int l15 = lane&15, half = lane>>4;
  const unsigned short* Wh = W2;
  const unsigned short* Wl = W2 + (size_t)M*K;
  const unsigned short* Xh = Xt + (size_t)b*(size_t)xbs;
  const unsigned short* Xl = Xh + (size_t)4096u*(size_t)K;

  facc acc[4][4];
  #pragma unroll
  for (int i=0;i<4;i++)
    #pragma unroll
    for (int j=0;j<4;j++) acc[i][j] = (facc){0.f,0.f,0.f,0.f};

  const size_t wrow[4] = {
    (size_t)(m0+wm+ 0+l15)*(size_t)K, (size_t)(m0+wm+16+l15)*(size_t)K,
    (size_t)(m0+wm+32+l15)*(size_t)K, (size_t)(m0+wm+48+l15)*(size_t)K };
  const size_t xrow[4] = {
    (size_t)(n0+wn+ 0+l15)*(size_t)K, (size_t)(n0+wn+16+l15)*(size_t)K,
    (size_t)(n0+wn+32+l15)*(size_t)K, (size_t)(n0+wn+48+l15)*(size_t)K };

  for (int k0=0; k0<K; k0+=32){
    int ks = k0 + half*8;
    bfrag ah[4], al[4], bh[4], bl[4];
    #pragma unroll
    for (int i=0;i<4;i++){
      ah[i] = *(const bfrag*)(Wh + wrow[i] + ks);
      al[i] = *(const bfrag*)(Wl + wrow[i] + ks);
      bh[i] = *(const bfrag*)(Xh + xrow[i] + ks);
      bl[i] = *(const bfrag*)(Xl + xrow[i] + ks);
    }
    #pragma unroll
    for (int i=0;i<4;i++)
      #pragma unroll
      for (int j=0;j<4;j++){
        acc[i][j] = __builtin_amdgcn_mfma_f32_16x16x32_bf16(ah[i], bh[j], acc[i][j],0,0,0);
        acc[i][j] = __builtin_amdgcn_mfma_f32_16x16x32_bf16(ah[i], bl[j], acc[i][j],0,0,0);
        acc[i][j] = __builtin_amdgcn_mfma_f32_16x16x32_bf16(al[i], bh[j], acc[i][j],0,0,0);
      }
  }
  #pragma unroll
  for (int i=0;i<4;i++){
    int o = m0+wm+i*16+half*4;
    #pragma unroll
    for (int j=0;j<4;j++){
      int p = n0+wn+j*16+l15;
      size_t ob = ((size_t)b*M + o)*(size_t)HW + p;
      #pragma unroll
      for (int r=0;r<4;r++)
        out[ob + (size_t)r*HW] = acc[i][j][r];
    }
  }
}

// ---------------------------------------------------------------------------
// plain bf16 MFMA GEMM
template<bool RES>
__global__ __launch_bounds__(256) void k_mfma1(
    const unsigned short* __restrict__ Wb,
    const unsigned short* __restrict__ Xt,
    const float* __restrict__ bias, const float* __restrict__ resid,
    float* __restrict__ out, int M, int K, long xbs){
  int b  = blockIdx.z;
  int n0 = blockIdx.x*128;
  int m0 = blockIdx.y*128;
  int wave = threadIdx.x>>6, lane = threadIdx.x&63;
  int wm = (wave>>1)*64, wn = (wave&1)*64;
  int l15 = lane&15, half = lane>>4;
  const unsigned short* Xh = Xt + (size_t)b*(size_t)xbs;

  facc acc[4][4];
  #pragma unroll
  for (int i=0;i<4;i++)
    #pragma unroll
    for (int j=0;j<4;j++) acc[i][j] = (facc){0.f,0.f,0.f,0.f};

  const size_t wrow[4] = {
    (size_t)(m0+wm+ 0+l15)*(size_t)K, (size_t)(m0+wm+16+l15)*(size_t)K,
    (size_t)(m0+wm+32+l15)*(size_t)K, (size_t)(m0+wm+48+l15)*(size_t)K };
  const size_t xrow[4] = {
    (size_t)(n0+wn+ 0+l15)*(size_t)K, (size_t)(n0+wn+16+l15)*(size_t)K,
    (size_t)(n0+wn+32+l15)*(size_t)K, (size_t)(n0+wn+48+l15)*(size_t)K };

  #pragma unroll 2
  for (int k0=0; k0<K; k0+=32){
    int ks = k0 + half*8;
    bfrag ah[4], bh[4];
    #pragma unroll
    for (int i=0;i<4;i++){
      ah[i] = *(const bfrag*)(Wb + wrow[i] + ks);
      bh[i] = *(const bfrag*)(Xh + xrow[i] + ks);
    }
    #pragma unroll
    for (int i=0;i<4;i++)
      #pragma unroll
      for (int j=0;j<4;j++)
        acc[i][j] = __builtin_amdgcn_mfma_f32_16x16x32_bf16(ah[i], bh[j], acc[i][j],0,0,0);
  }
  #pragma unroll
  for (int i=0;i<4;i++){
    int o = m0+wm+i*16+half*4;
    #pragma unroll
    for (int j=0;j<4;j++){
      int p = n0+wn+j*16+l15;
      size_t ob = ((size_t)b*M + o)*(size_t)HW + p;
      #pragma unroll
      for (int r=0;r<4;r++){
        float v = acc[i][j][r];
        if (bias) v += bias[o+r];
        if (RES)  v += resid[ob + (size_t)r*HW];
        out[ob + (size_t)r*HW] = v;
      }
    }
  }
}

// ---------------------------------------------------------------------------
// l2norm along W (vectorized float4, 16 lanes/row); in-place on q,k.
// Emits per-row sums: k rows -> k_height, q rows -> qrow.
__global__ __launch_bounds__(256) void k_l2norm(float* __restrict__ qkv,
    float* __restrict__ k_height, float* __restrict__ qrow){
  int row = blockIdx.x*16 + (threadIdx.x>>4);
  int l16 = threadIdx.x & 15;
  int part = row >> 17;
  int rem  = row & 131071;
  int Bp   = rem >> 11;
  int c    = (rem >> 6) & 31;
  int h    = rem & 63;
  int b = Bp>>3, hd = Bp&7;
  float* ptr = qkv + ((size_t)b*768 + part*256 + hd*32 + c)*(size_t)HW + h*64 + l16*4;
  float4 v = *(const float4*)ptr;
  float ss = v.x*v.x+v.y*v.y+v.z*v.z+v.w*v.w;
  float sv = v.x+v.y+v.z+v.w;
  #pragma unroll
  for (int d=1; d<16; d<<=1){ ss += __shfl_xor(ss,d,64); sv += __shfl_xor(sv,d,64); }
  float inv = 1.f / fmaxf(sqrtf(ss), 1e-12f);
  v.x*=inv; v.y*=inv; v.z*=inv; v.w*=inv;
  *(float4*)ptr = v;
  if (l16==0){
    float rsum = sv*inv;
    if (part) k_height[(size_t)Bp*2048 + c*64 + h] = rsum;
    else      qrow[(size_t)Bp*2048 + c*64 + h] = rsum;
  }
}

// q_probe[Bp][c] = sum_h qrow[Bp][c][h]
__global__ void k_qprobe2(const float* __restrict__ qrow, float* __restrict__ q_probe){
  int Bp = blockIdx.x; int t = threadIdx.x;
  int c = t>>3, h0 = (t&7)*8;
  float s = 0.f;
  #pragma unroll
  for (int j=0;j<8;j++) s += qrow[(size_t)Bp*2048 + c*64 + h0 + j];
  #pragma unroll
  for (int d=1; d<8; d<<=1) s += __shfl_xor(s,d,64);
  if ((t&7)==0) q_probe[Bp*32+c] = s;
}

// Q fp32 planar -> QT [Bp][4096][32] bf16 (post-l2norm)
__global__ __launch_bounds__(256) void k_qT(const float* __restrict__ qkv,
    unsigned short* __restrict__ qt){
  __shared__ float t[64][33];
  int Bp = blockIdx.y, p0 = blockIdx.x*64;
  int b = Bp>>3, hd = Bp&7;
  const float* qp = qkv + ((size_t)b*768 + hd*32)*(size_t)HW + p0;
  int c8 = threadIdx.x>>6, px = threadIdx.x&63;
  #pragma unroll
  for (int j=0;j<8;j++)
    t[px][c8*8+j] = qp[(size_t)(c8*8+j)*HW + px];
  __syncthreads();
  int px2 = threadIdx.x>>2, ch = threadIdx.x&3;
  us8 hv;
  #pragma unroll
  for (int j=0;j<8;j++) hv[j] = bf16r(t[px2][ch*8+j]);
  *(us8*)(qt + ((size_t)Bp*4096 + p0 + px2)*32 + ch*8) = hv;
}

__global__ void k_score(const float* __restrict__ q_probe,
    const float* __restrict__ agg, float* __restrict__ score){
  int Bp = blockIdx.x; int t = threadIdx.x;
  float s = 0.f;
  for (int c=0;c<32;c++) s += q_probe[Bp*32+c] * agg[(size_t)Bp*2048 + c*64 + t];
  score[Bp*64+t] = s;
}

__global__ void k_topk(const float* __restrict__ score, int* __restrict__ idx){
  int Bp = blockIdx.x; int lane = threadIdx.x;
  float v = score[Bp*64+lane];
  for (int it=0; it<16; ++it){
    float m = v;
    #pragma unroll
    for (int d=32; d; d>>=1) m = fmaxf(m, __shfl_xor(m,d,64));
    unsigned long long mask = __ballot(v==m);
    int sel = __ffsll((unsigned long long)mask) - 1;
    if (lane==0) idx[Bp*16+it] = sel;
    if (lane==sel) v = -3.0e38f;
  }
}

__global__ void k_kwidth(const float* __restrict__ qkv, const int* __restrict__ idx_h,
    float* __restrict__ k_width){
  int c = blockIdx.x, Bp = blockIdx.y, w = threadIdx.x;
  int b = Bp>>3, hd = Bp&7;
  const float* kp = qkv + ((size_t)b*768 + 256 + hd*32 + c)*(size_t)HW;
  float s = 0.f;
  for (int i=0;i<16;i++) s += kp[idx_h[Bp*16+i]*64 + w];
  k_width[(size_t)Bp*2048 + c*64 + w] = s;
}

// gather selected K [Bp][256][32] bf16 and V^T [Bp][32][256] bf16
__global__ __launch_bounds__(256) void k_gather_bf(const float* __restrict__ qkv,
    const int* __restrict__ idx_h, const int* __restrict__ idx_w,
    unsigned short* __restrict__ kfb, unsigned short* __restrict__ vtb){
  int Bp = blockIdx.x; int b = Bp>>3, hd = Bp&7;
  __shared__ int hi[16], wj[16];
  __shared__ int pos_s[256];
  if (threadIdx.x < 16) hi[threadIdx.x] = idx_h[Bp*16+threadIdx.x];
  else if (threadIdx.x < 32) wj[threadIdx.x-16] = idx_w[Bp*16+threadIdx.x-16];
  __syncthreads();
  pos_s[threadIdx.x] = hi[threadIdx.x>>4]*64 + wj[threadIdx.x&15];
  __syncthreads();
  const float* kpl = qkv + ((size_t)b*768 + 256 + hd*32)*(size_t)HW;
  const float* vpl = qkv + ((size_t)b*768 + 512 + hd*32)*(size_t)HW;
  for (int e=threadIdx.x; e<8192; e+=256){
    int t = e>>5, c = e&31;
    kfb[(size_t)Bp*8192 + e] = bf16r(kpl[(size_t)c*HW + pos_s[t]]);
    int c2 = e>>8, t2 = e&255;
    vtb[(size_t)Bp*8192 + e] = bf16r(vpl[(size_t)c2*HW + pos_s[t2]]);
  }
}

// ---------------------------------------------------------------------------
// MFMA attention: per block (Bp, 64-query tile); no max-tracking softmax.
__global__ __launch_bounds__(256) void k_attn_mfma(
    const unsigned short* __restrict__ QT,
    const unsigned short* __restrict__ kfb,
    const unsigned short* __restrict__ vtb,
    unsigned short* __restrict__ xout){
  __shared__ unsigned short Pl[4*16*264];
  __shared__ unsigned short obuf[4*16*32];
  __shared__ float lsum[64];
  int Bp = blockIdx.y, qb = blockIdx.x*64;
  int b = Bp>>3, hd = Bp&7;
  int tid = threadIdx.x;
  int wv = tid>>6, lane = tid&63, l15 = lane&15, lq = lane>>4;

  const unsigned short* Kg = kfb + (size_t)Bp*8192;
  const unsigned short* Vg = vtb + (size_t)Bp*8192;

  bfrag aq = *(const bfrag*)(QT + ((size_t)Bp*4096 + qb + wv*16 + l15)*32 + lq*8);

  float ps[4] = {0.f,0.f,0.f,0.f};
  #pragma unroll
  for (int t=0;t<16;t++){
    bfrag bk = *(const bfrag*)(Kg + (t*16+l15)*32 + lq*8);
    facc s = (facc){0.f,0.f,0.f,0.f};
    s = __builtin_amdgcn_mfma_f32_16x16x32_bf16(aq, bk, s, 0,0,0);
    #pragma unroll
    for (int r=0;r<4;r++){
      float pe = __expf(s[r]);
      ps[r] += pe;
      Pl[(wv*16 + lq*4 + r)*264 + t*16 + l15] = bf16r(pe);
    }
  }
  #pragma unroll
  for (int r=0;r<4;r++){
    #pragma unroll
    for (int d=1; d<16; d<<=1) ps[r] += __shfl_xor(ps[r], d, 64);
  }
  if (l15==0){
    #pragma unroll
    for (int r=0;r<4;r++) lsum[wv*16 + lq*4 + r] = ps[r];
  }

  facc o0 = (facc){0.f,0.f,0.f,0.f}, o1 = (facc){0.f,0.f,0.f,0.f};
  #pragma unroll
  for (int ko=0;ko<8;ko++){
    bfrag ap = *(const bfrag*)(Pl + (wv*16 + l15)*264 + ko*32 + lq*8);
    bfrag b0 = *(const bfrag*)(Vg + (l15)*256 + ko*32 + lq*8);
    bfrag b1 = *(const bfrag*)(Vg + (16+l15)*256 + ko*32 + lq*8);
    o0 = __builtin_amdgcn_mfma_f32_16x16x32_bf16(ap, b0, o0, 0,0,0);
    o1 = __builtin_amdgcn_mfma_f32_16x16x32_bf16(ap, b1, o1, 0,0,0);
  }
  #pragma unroll
  for (int r=0;r<4;r++){
    float iv = 1.f / lsum[wv*16 + lq*4 + r];
    obuf[(wv*16 + lq*4 + r)*32 + l15]      = bf16r(o0[r]*iv);
    obuf[(wv*16 + lq*4 + r)*32 + 16 + l15] = bf16r(o1[r]*iv);
  }
  int ql = wv*16 + (lane>>2), ch = lane&3;
  us8 hv = *(const us8*)(obuf + ql*32 + ch*8);
  *(us8*)(xout + (size_t)b*6291456ull + (size_t)(qb + ql)*256u + hd*32 + ch*8) = hv;
}

// ---------------------------------------------------------------------------
// fp32 planar -> bf16 transposed [wb][4096][Ktot] at coff; us8 coalesced writes
__global__ __launch_bounds__(256) void k_bf16T(const float* __restrict__ in,
    unsigned short* __restrict__ xt, int Cpart, int Ktot, int coff, int rb0, int wb0){
  int rb = rb0 + blockIdx.z, wb = wb0 + blockIdx.z;
  int c0 = blockIdx.y*64, p0 = blockIdx.x*64;
  __shared__ float t[64][65];
  const float* ip = in + ((size_t)rb*Cpart + c0)*(size_t)HW + p0;
  int tr = threadIdx.x>>4, tc4 = (threadIdx.x&15)*4;
  #pragma unroll
  for (int rr=0; rr<64; rr+=16){
    float4 v = *(const float4*)(ip + (size_t)(tr+rr)*HW + tc4);
    t[tr+rr][tc4+0]=v.x; t[tr+rr][tc4+1]=v.y; t[tr+rr][tc4+2]=v.z; t[tr+rr][tc4+3]=v.w;
  }
  __syncthreads();
  unsigned short* xh = xt + (size_t)wb*4096u*(size_t)Ktot + (size_t)coff + c0;
  int chunk = threadIdx.x & 7;
  #pragma unroll
  for (int i=0;i<2;i++){
    int pix = (threadIdx.x>>3) + 32*i;
    us8 hv;
    #pragma unroll
    for (int j=0;j<8;j++) hv[j] = bf16r(t[chunk*8+j][pix]);
    *(us8*)(xh + (size_t)(p0+pix)*(size_t)Ktot + chunk*8) = hv;
  }
}

// depthwise 3x3 + bf16 transposed write into XT2 cols [256,512); LDS-staged.
__global__ __launch_bounds__(256) void k_dwbf16(const float* __restrict__ x,
    const float* __restrict__ w, const float* __restrict__ bias,
    unsigned short* __restrict__ xt){
  __shared__ unsigned short lt[256*65];
  int tid = threadIdx.x;
  int p = blockIdx.x*256 + tid;
  int b = p >> 12, pos = p & 4095;
  int pos0 = (blockIdx.x*256) & 4095;
  int h = pos>>6, wx = pos&63;
  int c0 = blockIdx.y*64;
  for (int cc=0; cc<64; cc++){
    int c = c0+cc;
    const float* ip = x + ((size_t)b*Cd + c)*(size_t)HW;
    const float* wp = w + c*9;
    float s = bias[c];
    #pragma unroll
    for (int kh=-1; kh<=1; ++kh){
      int hh = h+kh; if ((unsigned)hh >= 64u) continue;
      #pragma unroll
      for (int kw=-1; kw<=1; ++kw){
        int ww2 = wx+kw; if ((unsigned)ww2 >= 64u) continue;
        s += wp[(kh+1)*3 + (kw+1)] * ip[hh*64 + ww2];
      }
    }
    lt[tid*65 + cc] = bf16r(s);
  }
  __syncthreads();
  int chunk = tid & 7;
  #pragma unroll
  for (int i=0;i<8;i++){
    int row = (tid>>3) + 32*i;
    us8 hv;
    #pragma unroll
    for (int j=0;j<8;j++) hv[j] = lt[row*65 + chunk*8 + j];
    *(us8*)(xt + (size_t)b*2097152ull + (size_t)(pos0+row)*512u + 256u + c0 + chunk*8) = hv;
  }
}

// ---------------------------------------------------------------------------
// FFN middle, conflict-free LDS + fast gelu. Pixel mapping px = i*256 + t
// (consecutive lanes -> consecutive LDS addresses -> no bank conflicts).
__global__ __launch_bounds__(256) void k_ffn_fused(float* __restrict__ h,
    const float* __restrict__ wdw, const float* __restrict__ bdw){
  __shared__ float lds[4096];
  __shared__ float red[8];
  int plane = blockIdx.x;
  int c = plane & 1023;
  float* hp = h + (size_t)plane*(size_t)HW;
  int t = threadIdx.x;
  int wid = t>>6, lane = t&63;

  // pass 1: stride-256 loads + stats
  float v[16];
  float s=0.f, ss=0.f;
  #pragma unroll
  for (int i=0;i<16;i++){
    v[i] = hp[i*256 + t];
    s += v[i]; ss += v[i]*v[i];
  }
  s = wredsum(s); ss = wredsum(ss);
  if (lane==0){ red[wid]=s; red[4+wid]=ss; }
  __syncthreads();
  s  = red[0]+red[1]+red[2]+red[3];
  ss = red[4]+red[5]+red[6]+red[7];
  float mean = s*(1.f/HW);
  float inv  = rsqrtf(ss*(1.f/HW) - mean*mean + 1e-5f);

  // h' = gelu(norm) -> LDS (conflict-free writes)
  #pragma unroll
  for (int i=0;i<16;i++)
    lds[i*256 + t] = gelu_fast((v[i]-mean)*inv);
  __syncthreads();

  // dwconv 3x3 from LDS (conflict-free reads) + stats of r
  float w9[9];
  #pragma unroll
  for (int i=0;i<9;i++) w9[i] = wdw[c*9+i];
  float bv = bdw[c];
  float r[16];
  float s2=0.f, ss2=0.f;
  #pragma unroll
  for (int i=0;i<16;i++){
    int px = i*256 + t;
    int hh = px>>6, ww = px&63;
    float acc = bv;
    #pragma unroll
    for (int kh=-1; kh<=1; ++kh){
      int h2 = hh+kh; if ((unsigned)h2 >= 64u) continue;
      #pragma unroll
      for (int kw=-1; kw<=1; ++kw){
        int w2 = ww+kw; if ((unsigned)w2 >= 64u) continue;
        acc += w9[(kh+1)*3+(kw+1)] * lds[h2*64 + w2];
      }
    }
    r[i] = acc;
    s2 += acc; ss2 += acc*acc;
  }
  s2 = wredsum(s2); ss2 = wredsum(ss2);
  __syncthreads();
  if (lane==0){ red[wid]=s2; red[4+wid]=ss2; }
  __syncthreads();
  s2  = red[0]+red[1]+red[2]+red[3];
  ss2 = red[4]+red[5]+red[6]+red[7];
  float mean2 = s2*(1.f/HW);
  float inv2  = rsqrtf(ss2*(1.f/HW) - mean2*mean2 + 1e-5f);

  // h = h' + gelu(norm2(r))
  #pragma unroll
  for (int i=0;i<16;i++){
    int px = i*256 + t;
    hp[px] = lds[px] + gelu_fast((r[i]-mean2)*inv2);
  }
}

// instance norm over HW per plane
__global__ __launch_bounds__(256) void k_instnorm(const float* __restrict__ in,
    float* __restrict__ out){
  size_t base = (size_t)blockIdx.x * HW;
  const float* p = in + base;
  float s=0.f, ss=0.f;
  for (int i=threadIdx.x*4; i<HW; i+=1024){
    float4 v = *(const float4*)(p+i);
    s  += v.x+v.y+v.z+v.w;
    ss += v.x*v.x+v.y*v.y+v.z*v.z+v.w*v.w;
  }
  s = wredsum(s); ss = wredsum(ss);
  __shared__ float sh[8];
  int wid = threadIdx.x>>6;
  if ((threadIdx.x&63)==0){ sh[wid]=s; sh[4+wid]=ss; }
  __syncthreads();
  s  = sh[0]+sh[1]+sh[2]+sh[3];
  ss = sh[4]+sh[5]+sh[6]+sh[7];
  float mean = s*(1.f/HW);
  float inv  = rsqrtf(ss*(1.f/HW) - mean*mean + 1e-5f);
  for (int i=threadIdx.x*4; i<HW; i+=1024){
    float4 v = *(const float4*)(p+i);
    float4 r;
    r.x = (v.x-mean)*inv; r.y = (v.y-mean)*inv; r.z = (v.z-mean)*inv; r.w = (v.w-mean)*inv;
    *(float4*)(out + base + i) = r;
  }
}

// ---------------------------------------------------------------------------
extern "C" void kernel_launch(void* const* d_in, const int* in_sizes, int n_in,
                              void* d_out, int out_size, void* d_ws, size_t ws_size,
                              hipStream_t stream){
  const float* x      = (const float*)d_in[0];
  const float* ln_g   = (const float*)d_in[1];
  const float* ln_bb  = (const float*)d_in[2];
  const float* w_qkv  = (const float*)d_in[3];
  const float* w_out  = (const float*)d_in[4];
  const float* b_out  = (const float*)d_in[5];
  const float* w_dw   = (const float*)d_in[6];
  const float* b_dw   = (const float*)d_in[7];
  const float* w_comb = (const float*)d_in[8];
  const float* b_comb = (const float*)d_in[9];
  const float* w_ff1  = (const float*)d_in[10];
  const float* b_ff1  = (const float*)d_in[11];
  const float* w_ffdw = (const float*)d_in[12];
  const float* b_ffdw = (const float*)d_in[13];
  const float* w_ff2  = (const float*)d_in[14];
  const float* b_ff2  = (const float*)d_in[15];
  float* out = (float*)d_out;
  float* ws  = (float*)d_ws;

  // ---- workspace (float offsets), ~163.5 MiB ----
  float* A    = ws;                                  // [0, 8.39M) attn_out / XT3a
  float* Q    = ws + 8388608ull;                     // [8.39M, 33.55M) qkv
  float* Hb   = ws + 8388608ull;                     // h (after qkv dead)
  float* F2o  = ws + 8388608ull;                     // ff2 fp32 out (after Hb dead)
  unsigned short* XT2 = (unsigned short*)(ws + 16777216ull);   // comb input bf16
  unsigned short* XTa = (unsigned short*)(ws + 33554432ull);   // qkv input (split)
  unsigned short* QT  = (unsigned short*)(ws + 33554432ull);   // reuse after qkv GEMM
  unsigned short* KFB = (unsigned short*)(ws + 37748736ull);   // K gathered bf16
  unsigned short* VTB = (unsigned short*)(ws + 38010880ull);   // V^T gathered bf16
  unsigned short* Xattn = (unsigned short*)(Q + 2097152ull);   // v-plane reuse
  unsigned short* XT3a = (unsigned short*)ws;                  // A region reuse
  unsigned short* XT3b = (unsigned short*)d_out;               // d_out reuse
  unsigned short* XTb  = (unsigned short*)d_out;               // ff1 input
  float* S = ws;                                     // attention smalls (in A region)
  float* k_height = S;                      // 131072
  float* k_width  = S + 131072;             // 131072
  float* qrow     = S + 262144;             // 131072
  float* q_probe  = S + 393216;             // 2048
  float* score_r  = S + 395264;             // 4096
  float* score_c  = S + 399360;             // 4096
  int*   idx_h    = (int*)(S + 403456);     // 1024
  int*   idx_w    = idx_h + 1024;           // 1024
  unsigned short* W2qkv = (unsigned short*)(ws + 41943040ull); // split 393216 us
  unsigned short* Wb_out  = W2qkv + 393216;          // 65536
  unsigned short* Wb_comb = Wb_out + 65536;          // 131072
  unsigned short* Wb_ff1  = Wb_comb + 131072;        // 262144
  unsigned short* Wb_ff2  = Wb_ff1 + 262144;         // 262144

  // weights
  k_splitW<<<(196608+255)/256, 256, 0, stream>>>(w_qkv, W2qkv, 196608);
  k_cvtW<<<(65536 +255)/256, 256, 0, stream>>>(w_out,  Wb_out,  65536);
  k_cvtW<<<(131072+255)/256, 256, 0, stream>>>(w_comb, Wb_comb, 131072);
  k_cvtW<<<(262144+255)/256, 256, 0, stream>>>(w_ff1,  Wb_ff1, 262144);
  k_cvtW<<<(262144+255)/256, 256, 0, stream>>>(w_ff2,  Wb_ff2, 262144);

  // ---- DPSA attention branch ----
  k_lnsplit<<<512, 256, 0, stream>>>(x, ln_g, ln_bb, XTa);
  k_mfma3<<<dim3(32,6,8), 256, 0, stream>>>(W2qkv, XTa, Q, 768, 256, 2097152);
  k_l2norm<<<16384, 256, 0, stream>>>(Q, k_height, qrow);
  k_qprobe2<<<64, 256, 0, stream>>>(qrow, q_probe);
  k_qT<<<dim3(64,64), 256, 0, stream>>>(Q, QT);
  k_score<<<64, 64, 0, stream>>>(q_probe, k_height, score_r);
  k_topk<<<64, 64, 0, stream>>>(score_r, idx_h);
  k_kwidth<<<dim3(32,64), 64, 0, stream>>>(Q, idx_h, k_width);
  k_score<<<64, 64, 0, stream>>>(q_probe, k_width, score_c);
  k_topk<<<64, 64, 0, stream>>>(score_c, idx_w);
  k_gather_bf<<<64, 256, 0, stream>>>(Q, idx_h, idx_w, KFB, VTB);
  k_attn_mfma<<<dim3(64,64), 256, 0, stream>>>(QT, KFB, VTB, Xattn);
  k_mfma1<false><<<dim3(32,2,8), 256, 0, stream>>>(Wb_out, Xattn, b_out, nullptr, (float*)d_out, 256, 256, 6291456);

  // ---- conv branch + combine + residual ----
  k_bf16T<<<dim3(64,4,8), 256, 0, stream>>>((const float*)d_out, XT2, 256, 512, 0, 0, 0);
  k_dwbf16<<<dim3(128,4), 256, 0, stream>>>(x, w_dw, b_dw, XT2);
  k_mfma1<true><<<dim3(32,2,8), 256, 0, stream>>>(Wb_comb, XT2, b_comb, x, A, 256, 512, 2097152);

  // ---- feedforward ----
  k_bf16T<<<dim3(64,4,8), 256, 0, stream>>>(A, XTb, 256, 256, 0, 0, 0);
  k_mfma1<false><<<dim3(32,8,8), 256, 0, stream>>>(Wb_ff1, XTb, b_ff1, nullptr, Hb, 1024, 256, 1048576);
  k_ffn_fused<<<Bn*1024, 256, 0, stream>>>(Hb, w_ffdw, b_ffdw);
  // h -> bf16 transposed: batches 0-3 into dead A region, 4-7 into dead d_out
  k_bf16T<<<dim3(64,16,4), 256, 0, stream>>>(Hb, XT3a, 1024, 1024, 0, 0, 0);
  k_bf16T<<<dim3(64,16,4), 256, 0, stream>>>(Hb, XT3b, 1024, 1024, 0, 4, 0);
  k_mfma1<false><<<dim3(32,2,4), 256, 0, stream>>>(Wb_ff2, XT3a, b_ff2, nullptr, F2o, 256, 1024, 4194304);
  k_mfma1<false><<<dim3(32,2,4), 256, 0, stream>>>(Wb_ff2, XT3b, b_ff2, nullptr, F2o + 4ull*256*HW, 256, 1024, 4194304);
  k_instnorm<<<Bn*256, 256, 0, stream>>>(F2o, (float*)d_out);
}